// Round 1
// baseline (2417.513 us; speedup 1.0000x reference)
//
#include <hip/hip_runtime.h>
#include <cstdint>
#include <cstddef>

// ---------------- constants ----------------
constexpr int NB = 4;          // batch
constexpr int HWP = 4096;      // H*W
// d_out offsets (floats)
constexpr size_t OUT_P1 = 0;
constexpr size_t OUT_P2 = 6291456;
constexpr size_t OUT_P3 = 12582912;
constexpr size_t OUT_S  = 18874368;
constexpr size_t OUT_U  = 18890752;
constexpr size_t OUT_RA = 18907136;

// ---------------- workspace layout (float elements) ----------------
constexpr size_t WS_SS    = 0;        // 16384
constexpr size_t WS_RNORM = 16384;    // 16384
constexpr size_t WS_YPROB = 32768;    // 16384
constexpr size_t WS_ARGI  = 49152;    // 16384 (int)
constexpr size_t WS_LSU   = 65536;    // 16384
constexpr size_t WS_PMAX  = 81920;    // 65536
constexpr size_t WS_PARG  = 147456;   // 65536 (int)
constexpr size_t WS_W5P   = 212992;   // 393216  (1536 x 256)
constexpr size_t WS_WRP   = 606208;   // 163840  (640 x 256)
constexpr size_t WS_W1AT  = 770048;   // 32768   (256 x 128)
constexpr size_t WS_W1BT  = 802816;   // 16384
constexpr size_t WS_W1CT  = 819200;   // 49152   (128 x 384)
constexpr size_t WS_W2ATL = 868352;   // 32768
constexpr size_t WS_W2ATR = 901120;   // 32768
constexpr size_t WS_W2BT  = 933888;   // 16384
constexpr size_t WS_W2CT  = 950272;   // 49152
constexpr size_t WS_W3ATLZ= 999424;   // 49152   (384 x 128)
constexpr size_t WS_W3ATR = 1048576;  // 32768
constexpr size_t WS_W3BT  = 1081344;  // 16384
constexpr size_t WS_W3CT  = 1097728;  // 49152
constexpr size_t WS_BIG   = 1146880;  // V: 8388608 ; later aliased: local + F
constexpr size_t WS_LOCAL = WS_BIG;                 // 4194304 (N,256,4096)
constexpr size_t WS_F     = WS_BIG + 4194304;       // 4194304 (N,256,4096)
constexpr size_t WS_P2    = WS_BIG + 8388608;       // 2097152
constexpr size_t WS_P3    = WS_P2 + 2097152;        // 2097152
constexpr size_t WS_HA    = WS_P3 + 2097152;        // 2097152
constexpr size_t WS_HB    = WS_HA + 2097152;        // 2097152

// tap encodings: 5 bits per tap: (dh+2) | ((dw+2)<<2)
constexpr uint64_t TENC(int i, int dh, int dw) {
    return ((uint64_t)((dh + 2) | ((dw + 2) << 2))) << (5 * i);
}
constexpr uint64_t ENC5 = TENC(0,-2,-2)|TENC(1,-2,-1)|TENC(2,-2,0)|TENC(3,-2,1)|TENC(4,-2,2)
                        | TENC(5,-1,-2)|TENC(6,-1,-1)|TENC(7,-1,0)|TENC(8,-1,1)|TENC(9,-1,2)
                        | TENC(10,0,-2)|TENC(11,0,-1);
constexpr uint64_t ENC3 = TENC(0,-1,-1)|TENC(1,-1,0)|TENC(2,-1,1)|TENC(3,0,-1)|TENC(4,0,0);

// ---------------- weight repack (one launch) ----------------
// dense repack: out[k*O + o] = in[o*Kin + koff + k]
__global__ __launch_bounds__(256) void repack_all(
    const float* __restrict__ w5, const float* __restrict__ wr,
    const float* __restrict__ w1a, const float* __restrict__ w1b, const float* __restrict__ w1c,
    const float* __restrict__ w2a, const float* __restrict__ w2b, const float* __restrict__ w2c,
    const float* __restrict__ w3a, const float* __restrict__ w3b, const float* __restrict__ w3c,
    float* __restrict__ ws)
{
    int idx = blockIdx.x * 256 + threadIdx.x;
    if (idx < 393216) { // conv5: (tap*128+c)*256 + o
        int o = idx & 255; int rem = idx >> 8; int c = rem & 127; int tp = rem >> 7;
        int f = (int)((ENC5 >> (5 * tp)) & 31);
        int dh = (f & 3) - 2, dw = ((f >> 2) & 7) - 2;
        ws[WS_W5P + idx] = w5[((size_t)(o * 128 + c)) * 25 + (dh + 2) * 5 + (dw + 2)];
        return;
    }
    idx -= 393216;
    if (idx < 163840) { // conv3
        int o = idx & 255; int rem = idx >> 8; int c = rem & 127; int tp = rem >> 7;
        int f = (int)((ENC3 >> (5 * tp)) & 31);
        int dh = (f & 3) - 2, dw = ((f >> 2) & 7) - 2;
        ws[WS_WRP + idx] = wr[((size_t)(o * 128 + c)) * 9 + (dh + 1) * 3 + (dw + 1)];
        return;
    }
    idx -= 163840;
    if (idx < 32768) { int o = idx & 127, k = idx >> 7; ws[WS_W1AT + idx] = w1a[o * 256 + k]; return; }
    idx -= 32768;
    if (idx < 16384) { int o = idx & 127, k = idx >> 7; ws[WS_W1BT + idx] = w1b[o * 128 + k]; return; }
    idx -= 16384;
    if (idx < 49152) { int o = idx % 384, k = idx / 384; ws[WS_W1CT + idx] = w1c[o * 128 + k]; return; }
    idx -= 49152;
    if (idx < 32768) { int o = idx & 127, k = idx >> 7; ws[WS_W2ATL + idx] = w2a[o * 512 + k]; return; }
    idx -= 32768;
    if (idx < 32768) { int o = idx & 127, k = idx >> 7; ws[WS_W2ATR + idx] = w2a[o * 512 + 256 + k]; return; }
    idx -= 32768;
    if (idx < 16384) { int o = idx & 127, k = idx >> 7; ws[WS_W2BT + idx] = w2b[o * 128 + k]; return; }
    idx -= 16384;
    if (idx < 49152) { int o = idx % 384, k = idx / 384; ws[WS_W2CT + idx] = w2c[o * 128 + k]; return; }
    idx -= 49152;
    if (idx < 49152) { // w3a local(256) + z(128) rows
        int o = idx & 127, k = idx >> 7;
        int srcc = (k < 256) ? k : (512 + (k - 256));
        ws[WS_W3ATLZ + idx] = w3a[o * 640 + srcc]; return;
    }
    idx -= 49152;
    if (idx < 32768) { int o = idx & 127, k = idx >> 7; ws[WS_W3ATR + idx] = w3a[o * 640 + 256 + k]; return; }
    idx -= 32768;
    if (idx < 16384) { int o = idx & 127, k = idx >> 7; ws[WS_W3BT + idx] = w3b[o * 128 + k]; return; }
    idx -= 16384;
    { int o = idx % 384, k = idx / 384; ws[WS_W3CT + idx] = w3c[o * 128 + k]; }
}

// ---------------- per-pixel sum of squares ----------------
__global__ __launch_bounds__(256) void sumsq_kernel(const float* __restrict__ y, float* __restrict__ ws)
{
    int idx = blockIdx.x * 256 + threadIdx.x; // n*4096+p
    int n = idx >> 12, p = idx & 4095;
    const float* yp = y + (size_t)n * 128 * 4096 + p;
    float s = 0.f;
    for (int c = 0; c < 128; ++c) { float v = yp[(size_t)c * 4096]; s += v * v; }
    ws[WS_SS + idx] = s;
}

// ---------------- reciprocal norm of masked neighborhood ----------------
__global__ __launch_bounds__(256) void rnorm_kernel(float* __restrict__ ws)
{
    int idx = blockIdx.x * 256 + threadIdx.x;
    int n = idx >> 12, p = idx & 4095;
    int h = p >> 6, w = p & 63;
    const float* ss = ws + WS_SS + ((size_t)n << 12);
    float nsq = 0.f;
    if (h > 0 && w > 0)  nsq += ss[p - 65];
    if (h > 0)           nsq += ss[p - 64];
    if (h > 0 && w < 63) nsq += ss[p - 63];
    if (w > 0)           nsq += ss[p - 1];
    ws[WS_RNORM + idx] = 1.0f / fmaxf(sqrtf(nsq), 1e-12f);
}

// ---------------- build normalized masked-neighborhood matrix V (n,512,4096) ----------------
__global__ __launch_bounds__(256) void vbuild_kernel(const float* __restrict__ y, float* __restrict__ ws)
{
    size_t idx = (size_t)blockIdx.x * 256 + threadIdx.x;
    int j = (int)(idx & 4095);
    int k = (int)((idx >> 12) & 511);
    int n = (int)(idx >> 21);
    int tp = k >> 7, c = k & 127;
    int h = j >> 6, w = j & 63;
    int off = 0; bool ok = false;
    if      (tp == 0) { ok = (h > 0) && (w > 0);  off = -65; }
    else if (tp == 1) { ok = (h > 0);             off = -64; }
    else if (tp == 2) { ok = (h > 0) && (w < 63); off = -63; }
    else              { ok = (w > 0);             off = -1;  }
    float v = 0.f;
    if (ok) v = y[(size_t)(n * 128 + c) * 4096 + j + off] * ws[WS_RNORM + ((size_t)n << 12) + j];
    ws[WS_BIG + idx] = v;
}

// ---------------- fused gram + column max/argmax (partial per i-chunk) ----------------
__global__ __launch_bounds__(256) void gram_kernel(
    const float* __restrict__ V, float* __restrict__ pmax, int* __restrict__ parg)
{
    int jb = blockIdx.x, ci = blockIdx.y, n = blockIdx.z;
    int j0 = jb << 7;
    int t = threadIdx.x;
    int tx = t & 15, ty = t >> 4;
    int jmaxi = j0 + 127;
    int ibeg = ci << 10;
    float* pm = pmax + (((size_t)n * 4 + ci) << 12);
    int* pa = parg + (((size_t)n * 4 + ci) << 12);
    if (ibeg >= jmaxi) {
        if (t < 128) { pm[j0 + t] = -INFINITY; pa[j0 + t] = 0x7fffffff; }
        return;
    }
    int iend = min(ibeg + 1024, jmaxi);
    __shared__ __align__(16) float As[32][128];
    __shared__ __align__(16) float Bs[32][128];
    __shared__ float redv[16][128];
    __shared__ int   redi[16][128];
    float bestv = -INFINITY; int besti = 0x7fffffff;
    const float* Vn = V + ((size_t)n << 21); // 512*4096
    int col = t & 127, rg = t >> 7;
    for (int ib = ibeg; ib < iend; ib += 128) {
        float acc[8][8];
        #pragma unroll
        for (int r = 0; r < 8; ++r)
            #pragma unroll
            for (int c2 = 0; c2 < 8; ++c2) acc[r][c2] = 0.f;
        for (int k0 = 0; k0 < 512; k0 += 32) {
            #pragma unroll
            for (int l = 0; l < 16; ++l) {
                int kk = rg * 16 + l;
                const float* vk = Vn + (size_t)(k0 + kk) * 4096;
                As[kk][col] = vk[ib + col];
                Bs[kk][col] = vk[j0 + col];
            }
            __syncthreads();
            #pragma unroll
            for (int k = 0; k < 32; ++k) {
                float4 a0 = *(const float4*)&As[k][ty * 8];
                float4 a1 = *(const float4*)&As[k][ty * 8 + 4];
                float4 b0 = *(const float4*)&Bs[k][tx * 8];
                float4 b1 = *(const float4*)&Bs[k][tx * 8 + 4];
                float aa[8] = {a0.x,a0.y,a0.z,a0.w,a1.x,a1.y,a1.z,a1.w};
                float bb[8] = {b0.x,b0.y,b0.z,b0.w,b1.x,b1.y,b1.z,b1.w};
                #pragma unroll
                for (int r = 0; r < 8; ++r)
                    #pragma unroll
                    for (int c2 = 0; c2 < 8; ++c2)
                        acc[r][c2] = fmaf(aa[r], bb[c2], acc[r][c2]);
            }
            __syncthreads();
        }
        // per-thread column reduction (i ascending), then cross-thread merge
        #pragma unroll
        for (int c2 = 0; c2 < 8; ++c2) {
            int j = j0 + tx * 8 + c2;
            float lv = -INFINITY; int li = 0x7fffffff;
            #pragma unroll
            for (int r = 0; r < 8; ++r) {
                int i = ib + ty * 8 + r;
                if (i < j) { float v = acc[r][c2]; if (v > lv) { lv = v; li = i; } }
            }
            redv[ty][tx * 8 + c2] = lv;
            redi[ty][tx * 8 + c2] = li;
        }
        __syncthreads();
        if (t < 128) {
            #pragma unroll
            for (int q = 0; q < 16; ++q) {
                float v = redv[q][t];
                if (v > bestv) { bestv = v; besti = redi[q][t]; }
            }
        }
        __syncthreads();
    }
    if (t < 128) { pm[j0 + t] = bestv; pa[j0 + t] = besti; }
}

// ---------------- generic fp32 tiled GEMM (1x1 conv): C = act(Wt^T X + b [+ gather]) ----------------
// Wt: (Ktot x Ot), row k holds all Ot outputs. X sources concatenated along K.
__global__ __launch_bounds__(256) void gemm_dense(
    const float* __restrict__ Wt, const float* __restrict__ bias,
    const float* __restrict__ X0, int c0,
    const float* __restrict__ X1, int c1,
    const float* __restrict__ X2, int c2,
    int Ktot, int Ot,
    const float* __restrict__ gatherP, const int* __restrict__ argIdx,
    int leaky, float* __restrict__ Cout)
{
    __shared__ __align__(16) float As[32][64];
    __shared__ __align__(16) float Bs[32][64];
    int t = threadIdx.x;
    int p0 = blockIdx.x << 6;
    int o0 = blockIdx.y << 6;
    int n = blockIdx.z;
    int tx = t & 15, ty = t >> 4;
    int lw = t & 63, lr = t >> 6;
    float acc[4][4] = {};
    for (int k0 = 0; k0 < Ktot; k0 += 32) {
        #pragma unroll
        for (int l = 0; l < 8; ++l) {
            int kk = lr * 8 + l;
            As[kk][lw] = Wt[(size_t)(k0 + kk) * Ot + o0 + lw];
        }
        #pragma unroll
        for (int l = 0; l < 8; ++l) {
            int kk = lr * 8 + l; int kg = k0 + kk;
            const float* src; int kl, cs;
            if (kg < c0) { src = X0; kl = kg; cs = c0; }
            else if (kg < c0 + c1) { src = X1; kl = kg - c0; cs = c1; }
            else { src = X2; kl = kg - c0 - c1; cs = c2; }
            Bs[kk][lw] = src[((size_t)n * cs + kl) * 4096 + p0 + lw];
        }
        __syncthreads();
        #pragma unroll
        for (int k = 0; k < 32; ++k) {
            float4 av = *(const float4*)&As[k][ty << 2];
            float4 bv = *(const float4*)&Bs[k][tx << 2];
            float a4[4] = {av.x, av.y, av.z, av.w};
            float b4[4] = {bv.x, bv.y, bv.z, bv.w};
            #pragma unroll
            for (int i = 0; i < 4; ++i)
                #pragma unroll
                for (int j2 = 0; j2 < 4; ++j2)
                    acc[i][j2] = fmaf(a4[i], b4[j2], acc[i][j2]);
        }
        __syncthreads();
    }
    #pragma unroll
    for (int i = 0; i < 4; ++i) {
        int o = o0 + (ty << 2) + i;
        float bv = bias ? bias[o] : 0.f;
        #pragma unroll
        for (int j2 = 0; j2 < 4; ++j2) {
            int p = p0 + (tx << 2) + j2;
            float v = acc[i][j2] + bv;
            if (gatherP) {
                int aj = argIdx[(n << 12) + p];
                if (aj >= 0) v += gatherP[((size_t)n * Ot + o) * 4096 + aj];
            }
            if (leaky) v = v > 0.f ? v : 0.2f * v;
            Cout[((size_t)n * Ot + o) * 4096 + p] = v;
        }
    }
}

// ---------------- masked conv as implicit GEMM (tile = one image row x 64 outch) ----------------
__global__ __launch_bounds__(256) void gemm_conv(
    const float* __restrict__ Wp, const float* __restrict__ bias,
    const float* __restrict__ Y, uint64_t tapenc, int ntaps, int Ot,
    float* __restrict__ Cout)
{
    __shared__ __align__(16) float As[32][64];
    __shared__ __align__(16) float Bs[32][64];
    int t = threadIdx.x;
    int h = blockIdx.x;          // p0 = h*64
    int o0 = blockIdx.y << 6;
    int n = blockIdx.z;
    int tx = t & 15, ty = t >> 4;
    int lw = t & 63, lr = t >> 6;
    int Ktot = ntaps << 7;
    float acc[4][4] = {};
    for (int k0 = 0; k0 < Ktot; k0 += 32) {
        #pragma unroll
        for (int l = 0; l < 8; ++l) {
            int kk = lr * 8 + l;
            As[kk][lw] = Wp[(size_t)(k0 + kk) * Ot + o0 + lw];
        }
        {
            int tp = k0 >> 7; // 32-chunk always within one tap (128 | 32)
            int f = (int)((tapenc >> (5 * tp)) & 31);
            int dh = (f & 3) - 2, dw = ((f >> 2) & 7) - 2;
            int r = h + dh; int cw = lw + dw;
            bool okv = (r >= 0) && (r < 64) && (cw >= 0) && (cw < 64);
            #pragma unroll
            for (int l = 0; l < 8; ++l) {
                int kk = lr * 8 + l; int c = (k0 + kk) & 127;
                Bs[kk][lw] = okv ? Y[((size_t)(n * 128 + c) * 64 + r) * 64 + cw] : 0.f;
            }
        }
        __syncthreads();
        #pragma unroll
        for (int k = 0; k < 32; ++k) {
            float4 av = *(const float4*)&As[k][ty << 2];
            float4 bv = *(const float4*)&Bs[k][tx << 2];
            float a4[4] = {av.x, av.y, av.z, av.w};
            float b4[4] = {bv.x, bv.y, bv.z, bv.w};
            #pragma unroll
            for (int i = 0; i < 4; ++i)
                #pragma unroll
                for (int j2 = 0; j2 < 4; ++j2)
                    acc[i][j2] = fmaf(a4[i], b4[j2], acc[i][j2]);
        }
        __syncthreads();
    }
    #pragma unroll
    for (int i = 0; i < 4; ++i) {
        int o = o0 + (ty << 2) + i;
        float bv = bias ? bias[o] : 0.f;
        #pragma unroll
        for (int j2 = 0; j2 < 4; ++j2) {
            int p = (h << 6) + (tx << 2) + j2;
            Cout[((size_t)n * Ot + o) * 4096 + p] = acc[i][j2] + bv;
        }
    }
}

// ---------------- y_prob from para1 ----------------
__global__ __launch_bounds__(256) void yprob_kernel(
    const float* __restrict__ out, const float* __restrict__ y, float* __restrict__ ws)
{
    int idx = blockIdx.x * 256 + threadIdx.x;
    int n = idx >> 12, p = idx & 4095;
    const float* pw = out + OUT_P1 + (size_t)n * 384 * 4096 + p;
    const float* pm = pw + (size_t)128 * 4096;
    const float* psv = pm + (size_t)128 * 4096;
    const float* yy = y + (size_t)n * 128 * 4096 + p;
    float accs = 0.f;
    for (int c = 0; c < 128; ++c) {
        float w  = pw[(size_t)c * 4096];
        float mu = pm[(size_t)c * 4096];
        float ls = psv[(size_t)c * 4096];
        ls = fminf(fmaxf(ls, -7.f), 7.f);
        float tt = (yy[(size_t)c * 4096] - mu) * expf(-ls);
        float lsig = (w >= 0.f) ? -log1pf(expf(-w)) : (w - log1pf(expf(w)));
        float nll = 0.5f * tt * tt + ls + 0.9189385f - lsig;
        accs += expf(-nll);
    }
    ws[WS_YPROB + idx] = accs * (1.0f / 128.0f);
}

// ---------------- merge chunks, emit S/U/R_arg + gather index + log-sum ----------------
__global__ __launch_bounds__(256) void finalize_kernel(float* __restrict__ ws, float* __restrict__ out)
{
    int idx = blockIdx.x * 256 + threadIdx.x;
    int n = idx >> 12, j = idx & 4095;
    float s, u; int a;
    if (j == 0) { s = 1e-8f; u = 1e-8f; a = -1; }
    else {
        float bv = -INFINITY; int bi = 0x7fffffff;
        const int* pai = (const int*)ws;
        #pragma unroll
        for (int ci = 0; ci < 4; ++ci) {
            float v = ws[WS_PMAX + (((size_t)n * 4 + ci) << 12) + j];
            int ii = pai[WS_PARG + (((size_t)n * 4 + ci) << 12) + j];
            if (v > bv) { bv = v; bi = ii; }
        }
        s = fminf(fmaxf(bv, 1e-8f), 1.0f);
        float yp = ws[WS_YPROB + ((size_t)n << 12) + bi];
        u = fminf(fmaxf(yp, 1e-8f), 1.0f);
        a = bi;
    }
    out[OUT_S + idx] = s;
    out[OUT_U + idx] = u;
    out[OUT_RA + idx] = (float)a;
    ((int*)ws)[WS_ARGI + idx] = a;
    ws[WS_LSU + idx] = logf(s + 1e-8f) + logf(u + 1e-8f);
}

// ---------------- para2[:,0] += log(S)+log(U) ----------------
__global__ __launch_bounds__(256) void para2add_kernel(float* __restrict__ out, const float* __restrict__ ws)
{
    int idx = blockIdx.x * 256 + threadIdx.x; // N*128*4096
    int p = idx & 4095; int c = (idx >> 12) & 127; int n = idx >> 19;
    out[OUT_P2 + ((size_t)(n * 384 + c) << 12) + p] += ws[WS_LSU + ((size_t)n << 12) + p];
}

// ---------------- launch ----------------
extern "C" void kernel_launch(void* const* d_in, const int* in_sizes, int n_in,
                              void* d_out, int out_size, void* d_ws, size_t ws_size,
                              hipStream_t stream)
{
    const float* y   = (const float*)d_in[0];
    const float* z   = (const float*)d_in[1];
    const float* w5  = (const float*)d_in[2];
    const float* b5  = (const float*)d_in[3];
    const float* w1a = (const float*)d_in[4];
    const float* b1a = (const float*)d_in[5];
    const float* w1b = (const float*)d_in[6];
    const float* b1b = (const float*)d_in[7];
    const float* w1c = (const float*)d_in[8];
    const float* b1c = (const float*)d_in[9];
    const float* wrf = (const float*)d_in[10];
    const float* w2a = (const float*)d_in[11];
    const float* b2a = (const float*)d_in[12];
    const float* w2b = (const float*)d_in[13];
    const float* b2b = (const float*)d_in[14];
    const float* w2c = (const float*)d_in[15];
    const float* b2c = (const float*)d_in[16];
    const float* w3a = (const float*)d_in[17];
    const float* b3a = (const float*)d_in[18];
    const float* w3b = (const float*)d_in[19];
    const float* b3b = (const float*)d_in[20];
    const float* w3c = (const float*)d_in[21];
    const float* b3c = (const float*)d_in[22];
    float* ws  = (float*)d_ws;
    float* out = (float*)d_out;
    const int* argi = (const int*)(ws) + WS_ARGI;

    repack_all<<<3648, 256, 0, stream>>>(w5, wrf, w1a, w1b, w1c, w2a, w2b, w2c, w3a, w3b, w3c, ws);
    sumsq_kernel<<<64, 256, 0, stream>>>(y, ws);
    rnorm_kernel<<<64, 256, 0, stream>>>(ws);
    vbuild_kernel<<<32768, 256, 0, stream>>>(y, ws);
    gram_kernel<<<dim3(32, 4, NB), 256, 0, stream>>>(ws + WS_BIG, ws + WS_PMAX, (int*)(ws + WS_PARG));

    // conv5 -> local (overwrites V region; gram already done, stream-ordered)
    gemm_conv<<<dim3(64, 4, NB), 256, 0, stream>>>(ws + WS_W5P, b5, y, ENC5, 12, 256, ws + WS_LOCAL);

    // mlp1 -> para1
    gemm_dense<<<dim3(64, 2, NB), 256, 0, stream>>>(ws + WS_W1AT, b1a, ws + WS_LOCAL, 256, nullptr, 0, nullptr, 0,
                                                    256, 128, nullptr, nullptr, 1, ws + WS_HA);
    gemm_dense<<<dim3(64, 2, NB), 256, 0, stream>>>(ws + WS_W1BT, b1b, ws + WS_HA, 128, nullptr, 0, nullptr, 0,
                                                    128, 128, nullptr, nullptr, 1, ws + WS_HB);
    gemm_dense<<<dim3(64, 6, NB), 256, 0, stream>>>(ws + WS_W1CT, b1c, ws + WS_HB, 128, nullptr, 0, nullptr, 0,
                                                    128, 384, nullptr, nullptr, 0, out + OUT_P1);

    yprob_kernel<<<64, 256, 0, stream>>>(out, y, ws);
    finalize_kernel<<<64, 256, 0, stream>>>(ws, out);

    // masked conv3 -> F, then rf projections
    gemm_conv<<<dim3(64, 4, NB), 256, 0, stream>>>(ws + WS_WRP, nullptr, y, ENC3, 5, 256, ws + WS_F);
    gemm_dense<<<dim3(64, 2, NB), 256, 0, stream>>>(ws + WS_W2ATR, nullptr, ws + WS_F, 256, nullptr, 0, nullptr, 0,
                                                    256, 128, nullptr, nullptr, 0, ws + WS_P2);
    gemm_dense<<<dim3(64, 2, NB), 256, 0, stream>>>(ws + WS_W3ATR, nullptr, ws + WS_F, 256, nullptr, 0, nullptr, 0,
                                                    256, 128, nullptr, nullptr, 0, ws + WS_P3);

    // mlp2 -> para2 (+ log terms)
    gemm_dense<<<dim3(64, 2, NB), 256, 0, stream>>>(ws + WS_W2ATL, b2a, ws + WS_LOCAL, 256, nullptr, 0, nullptr, 0,
                                                    256, 128, ws + WS_P2, argi, 1, ws + WS_HA);
    gemm_dense<<<dim3(64, 2, NB), 256, 0, stream>>>(ws + WS_W2BT, b2b, ws + WS_HA, 128, nullptr, 0, nullptr, 0,
                                                    128, 128, nullptr, nullptr, 1, ws + WS_HB);
    gemm_dense<<<dim3(64, 6, NB), 256, 0, stream>>>(ws + WS_W2CT, b2c, ws + WS_HB, 128, nullptr, 0, nullptr, 0,
                                                    128, 384, nullptr, nullptr, 0, out + OUT_P2);
    para2add_kernel<<<8192, 256, 0, stream>>>(out, ws);

    // mlp3 -> para3
    gemm_dense<<<dim3(64, 2, NB), 256, 0, stream>>>(ws + WS_W3ATLZ, b3a, ws + WS_LOCAL, 256, z, 128, nullptr, 0,
                                                    384, 128, ws + WS_P3, argi, 1, ws + WS_HA);
    gemm_dense<<<dim3(64, 2, NB), 256, 0, stream>>>(ws + WS_W3BT, b3b, ws + WS_HA, 128, nullptr, 0, nullptr, 0,
                                                    128, 128, nullptr, nullptr, 1, ws + WS_HB);
    gemm_dense<<<dim3(64, 6, NB), 256, 0, stream>>>(ws + WS_W3CT, b3c, ws + WS_HB, 128, nullptr, 0, nullptr, 0,
                                                    128, 384, nullptr, nullptr, 0, out + OUT_P3);
    (void)in_sizes; (void)n_in; (void)out_size; (void)ws_size;
}

// Round 2
// 1096.501 us; speedup vs baseline: 2.2048x; 2.2048x over previous
//
#include <hip/hip_runtime.h>
#include <cstdint>
#include <cstddef>

typedef unsigned short ushort_t;
typedef __attribute__((ext_vector_type(8))) short bf16x8;
typedef __attribute__((ext_vector_type(4))) float f32x4;

#if defined(__has_builtin)
#if __has_builtin(__builtin_amdgcn_global_load_lds)
#define HAVE_GLL 1
#endif
#endif

// ---------------- constants ----------------
constexpr int NB = 4;          // batch
// d_out offsets (floats)
constexpr size_t OUT_P1 = 0;
constexpr size_t OUT_P2 = 6291456;
constexpr size_t OUT_P3 = 12582912;
constexpr size_t OUT_S  = 18874368;
constexpr size_t OUT_U  = 18890752;
constexpr size_t OUT_RA = 18907136;

// ---------------- workspace layout (float elements) ----------------
constexpr size_t WS_SS    = 0;        // 16384
constexpr size_t WS_RNORM = 16384;    // 16384
constexpr size_t WS_YPROB = 32768;    // 16384
constexpr size_t WS_ARGI  = 49152;    // 16384 (int)
constexpr size_t WS_LSU   = 65536;    // 16384
constexpr size_t WS_PMAX  = 81920;    // 524288 (n,32,4096)
constexpr size_t WS_PARG  = 606208;   // 524288 (int)
constexpr size_t WS_W5P   = 1130496;  // 393216  (1536 x 256)
constexpr size_t WS_WRP   = 1523712;  // 163840  (640 x 256)
constexpr size_t WS_W1AT  = 1687552;  // 32768   (256 x 128)
constexpr size_t WS_W1BT  = 1720320;  // 16384
constexpr size_t WS_W1CT  = 1736704;  // 49152   (128 x 384)
constexpr size_t WS_W2ATL = 1785856;  // 32768
constexpr size_t WS_W2ATR = 1818624;  // 32768
constexpr size_t WS_W2BT  = 1851392;  // 16384
constexpr size_t WS_W2CT  = 1867776;  // 49152
constexpr size_t WS_W3ATLZ= 1916928;  // 49152   (384 x 128)
constexpr size_t WS_W3ATR = 1966080;  // 32768
constexpr size_t WS_W3BT  = 1998848;  // 16384
constexpr size_t WS_W3CT  = 2015232;  // 49152
constexpr size_t WS_BIG   = 2064384;
// Vt bf16 hi/lo: each (n,4096,512) ushort = 4194304 floats
constexpr size_t WS_VH    = WS_BIG;                  // 4194304 floats (as ushort[8388608])
constexpr size_t WS_VL    = WS_BIG + 4194304;        // 4194304 floats
// aliased after gram completes:
constexpr size_t WS_LOCAL = WS_BIG;                  // 4194304 (N,256,4096)
constexpr size_t WS_F     = WS_BIG + 4194304;        // 4194304 (N,256,4096)
constexpr size_t WS_P2    = WS_BIG + 8388608;        // 2097152
constexpr size_t WS_P3    = WS_P2 + 2097152;         // 2097152
constexpr size_t WS_HA    = WS_P3 + 2097152;         // 2097152
constexpr size_t WS_HB    = WS_HA + 2097152;         // 2097152

// tap encodings: 5 bits per tap: (dh+2) | ((dw+2)<<2)
constexpr uint64_t TENC(int i, int dh, int dw) {
    return ((uint64_t)((dh + 2) | ((dw + 2) << 2))) << (5 * i);
}
constexpr uint64_t ENC5 = TENC(0,-2,-2)|TENC(1,-2,-1)|TENC(2,-2,0)|TENC(3,-2,1)|TENC(4,-2,2)
                        | TENC(5,-1,-2)|TENC(6,-1,-1)|TENC(7,-1,0)|TENC(8,-1,1)|TENC(9,-1,2)
                        | TENC(10,0,-2)|TENC(11,0,-1);
constexpr uint64_t ENC3 = TENC(0,-1,-1)|TENC(1,-1,0)|TENC(2,-1,1)|TENC(3,0,-1)|TENC(4,0,0);

static __device__ inline ushort_t f2bf_rne(float f) {
    uint32_t u = __float_as_uint(f);
    uint32_t r = (u + 0x7fffu + ((u >> 16) & 1u)) >> 16;
    return (ushort_t)r;
}
static __device__ inline float bf2f(ushort_t h) {
    return __uint_as_float(((uint32_t)h) << 16);
}

// global->LDS 16B stage: dest = ldsbase + lane*16 (HW), src per-lane
static __device__ inline void gll16(const ushort_t* g, ushort_t* l) {
#ifdef HAVE_GLL
    __builtin_amdgcn_global_load_lds((const __attribute__((address_space(1))) void*)g,
                                     (__attribute__((address_space(3))) void*)l, 16, 0, 0);
#else
    uint4 v = *(const uint4*)g;
    *(uint4*)((char*)l + (threadIdx.x & 63) * 16) = v;
#endif
}

// ---------------- weight repack (one launch) ----------------
__global__ __launch_bounds__(256) void repack_all(
    const float* __restrict__ w5, const float* __restrict__ wr,
    const float* __restrict__ w1a, const float* __restrict__ w1b, const float* __restrict__ w1c,
    const float* __restrict__ w2a, const float* __restrict__ w2b, const float* __restrict__ w2c,
    const float* __restrict__ w3a, const float* __restrict__ w3b, const float* __restrict__ w3c,
    float* __restrict__ ws)
{
    int idx = blockIdx.x * 256 + threadIdx.x;
    if (idx < 393216) { // conv5: (tap*128+c)*256 + o
        int o = idx & 255; int rem = idx >> 8; int c = rem & 127; int tp = rem >> 7;
        int f = (int)((ENC5 >> (5 * tp)) & 31);
        int dh = (f & 3) - 2, dw = ((f >> 2) & 7) - 2;
        ws[WS_W5P + idx] = w5[((size_t)(o * 128 + c)) * 25 + (dh + 2) * 5 + (dw + 2)];
        return;
    }
    idx -= 393216;
    if (idx < 163840) { // conv3
        int o = idx & 255; int rem = idx >> 8; int c = rem & 127; int tp = rem >> 7;
        int f = (int)((ENC3 >> (5 * tp)) & 31);
        int dh = (f & 3) - 2, dw = ((f >> 2) & 7) - 2;
        ws[WS_WRP + idx] = wr[((size_t)(o * 128 + c)) * 9 + (dh + 1) * 3 + (dw + 1)];
        return;
    }
    idx -= 163840;
    if (idx < 32768) { int o = idx & 127, k = idx >> 7; ws[WS_W1AT + idx] = w1a[o * 256 + k]; return; }
    idx -= 32768;
    if (idx < 16384) { int o = idx & 127, k = idx >> 7; ws[WS_W1BT + idx] = w1b[o * 128 + k]; return; }
    idx -= 16384;
    if (idx < 49152) { int o = idx % 384, k = idx / 384; ws[WS_W1CT + idx] = w1c[o * 128 + k]; return; }
    idx -= 49152;
    if (idx < 32768) { int o = idx & 127, k = idx >> 7; ws[WS_W2ATL + idx] = w2a[o * 512 + k]; return; }
    idx -= 32768;
    if (idx < 32768) { int o = idx & 127, k = idx >> 7; ws[WS_W2ATR + idx] = w2a[o * 512 + 256 + k]; return; }
    idx -= 32768;
    if (idx < 16384) { int o = idx & 127, k = idx >> 7; ws[WS_W2BT + idx] = w2b[o * 128 + k]; return; }
    idx -= 16384;
    if (idx < 49152) { int o = idx % 384, k = idx / 384; ws[WS_W2CT + idx] = w2c[o * 128 + k]; return; }
    idx -= 49152;
    if (idx < 49152) { // w3a local(256) + z(128) rows
        int o = idx & 127, k = idx >> 7;
        int srcc = (k < 256) ? k : (512 + (k - 256));
        ws[WS_W3ATLZ + idx] = w3a[o * 640 + srcc]; return;
    }
    idx -= 49152;
    if (idx < 32768) { int o = idx & 127, k = idx >> 7; ws[WS_W3ATR + idx] = w3a[o * 640 + 256 + k]; return; }
    idx -= 32768;
    if (idx < 16384) { int o = idx & 127, k = idx >> 7; ws[WS_W3BT + idx] = w3b[o * 128 + k]; return; }
    idx -= 16384;
    { int o = idx % 384, k = idx / 384; ws[WS_W3CT + idx] = w3c[o * 128 + k]; }
}

// ---------------- per-pixel sum of squares ----------------
__global__ __launch_bounds__(256) void sumsq_kernel(const float* __restrict__ y, float* __restrict__ ws)
{
    int idx = blockIdx.x * 256 + threadIdx.x; // n*4096+p
    int n = idx >> 12, p = idx & 4095;
    const float* yp = y + (size_t)n * 128 * 4096 + p;
    float s = 0.f;
    for (int c = 0; c < 128; ++c) { float v = yp[(size_t)c * 4096]; s += v * v; }
    ws[WS_SS + idx] = s;
}

// ---------------- reciprocal norm of masked neighborhood ----------------
__global__ __launch_bounds__(256) void rnorm_kernel(float* __restrict__ ws)
{
    int idx = blockIdx.x * 256 + threadIdx.x;
    int n = idx >> 12, p = idx & 4095;
    int h = p >> 6, w = p & 63;
    const float* ss = ws + WS_SS + ((size_t)n << 12);
    float nsq = 0.f;
    if (h > 0 && w > 0)  nsq += ss[p - 65];
    if (h > 0)           nsq += ss[p - 64];
    if (h > 0 && w < 63) nsq += ss[p - 63];
    if (w > 0)           nsq += ss[p - 1];
    ws[WS_RNORM + idx] = 1.0f / fmaxf(sqrtf(nsq), 1e-12f);
}

// ---------------- build normalized masked-neighborhood bf16 hi/lo, transposed Vt[n][j][k] ----------------
__global__ __launch_bounds__(256) void vbuild_kernel(const float* __restrict__ y, float* __restrict__ ws)
{
    size_t idx = (size_t)blockIdx.x * 256 + threadIdx.x; // (n*4096 + j)*512 + k
    int k = (int)(idx & 511);
    int j = (int)((idx >> 9) & 4095);
    int n = (int)(idx >> 21);
    int tp = k >> 7, c = k & 127;
    int h = j >> 6, w = j & 63;
    int off = 0; bool ok = false;
    if      (tp == 0) { ok = (h > 0) && (w > 0);  off = -65; }
    else if (tp == 1) { ok = (h > 0);             off = -64; }
    else if (tp == 2) { ok = (h > 0) && (w < 63); off = -63; }
    else              { ok = (w > 0);             off = -1;  }
    float v = 0.f;
    if (ok) v = y[(size_t)(n * 128 + c) * 4096 + j + off] * ws[WS_RNORM + ((size_t)n << 12) + j];
    ushort_t hi = f2bf_rne(v);
    float fhi = bf2f(hi);
    ushort_t lo = f2bf_rne(v - fhi);
    ushort_t* VH = (ushort_t*)(ws + WS_VH);
    ushort_t* VL = (ushort_t*)(ws + WS_VL);
    VH[idx] = hi;
    VL[idx] = lo;
}

// ---------------- MFMA split-bf16 gram + per-tile column max/argmax ----------------
// block = one triangle tile (ib<=jb), 256 threads = 4 waves, wave quadrant 64x64.
__global__ __launch_bounds__(256) void gram_mfma(const ushort_t* __restrict__ VH,
                                                 const ushort_t* __restrict__ VL,
                                                 float* __restrict__ pmax, int* __restrict__ parg)
{
    __shared__ __align__(16) ushort_t AsH[128 * 32];
    __shared__ __align__(16) ushort_t AsL[128 * 32];
    __shared__ __align__(16) ushort_t BsH[128 * 32];
    __shared__ __align__(16) ushort_t BsL[128 * 32];
    __shared__ float sredv[256];
    __shared__ int   sredi[256];

    int tb = blockIdx.x, n = blockIdx.y;
    int jb = (int)((sqrtf(8.0f * (float)tb + 1.0f) - 1.0f) * 0.5f);
    while ((jb + 1) * (jb + 2) / 2 <= tb) ++jb;
    while (jb * (jb + 1) / 2 > tb) --jb;
    int ib = tb - jb * (jb + 1) / 2;

    int t = threadIdx.x, lane = t & 63, w = t >> 6;
    int wq_i = w >> 1, wq_j = w & 1;
    int fr = lane & 15, kg = lane >> 4;

    const ushort_t* vhn = VH + ((size_t)n << 21); // n*4096*512
    const ushort_t* vln = VL + ((size_t)n << 21);

    // staging: per wave, 2 chunks of 16 cols; lane -> (col, kslot)
    int colq = lane >> 2, ks = lane & 3;
    int c0 = (w * 2 + 0) * 16 + colq;
    int c1 = (w * 2 + 1) * 16 + colq;
    size_t sA0 = ((size_t)(ib * 128 + c0)) * 512 + ks * 8;
    size_t sA1 = ((size_t)(ib * 128 + c1)) * 512 + ks * 8;
    size_t sB0 = ((size_t)(jb * 128 + c0)) * 512 + ks * 8;
    size_t sB1 = ((size_t)(jb * 128 + c1)) * 512 + ks * 8;
    int d0 = (w * 2 + 0) * 512; // ushort idx of wave chunk base (1KB each)
    int d1 = (w * 2 + 1) * 512;

    f32x4 acc[4][4];
    #pragma unroll
    for (int mi = 0; mi < 4; ++mi)
        #pragma unroll
        for (int ni = 0; ni < 4; ++ni)
            acc[mi][ni] = (f32x4){0.f, 0.f, 0.f, 0.f};

    for (int k0 = 0; k0 < 512; k0 += 32) {
        gll16(vhn + sA0 + k0, &AsH[d0]);
        gll16(vhn + sA1 + k0, &AsH[d1]);
        gll16(vln + sA0 + k0, &AsL[d0]);
        gll16(vln + sA1 + k0, &AsL[d1]);
        gll16(vhn + sB0 + k0, &BsH[d0]);
        gll16(vhn + sB1 + k0, &BsH[d1]);
        gll16(vln + sB0 + k0, &BsL[d0]);
        gll16(vln + sB1 + k0, &BsL[d1]);
#ifdef HAVE_GLL
        asm volatile("s_waitcnt vmcnt(0)" ::: "memory");
#endif
        __syncthreads();

        bf16x8 ah[4], al[4], bh[4], bl[4];
        #pragma unroll
        for (int mi = 0; mi < 4; ++mi) {
            int col = wq_i * 64 + mi * 16 + fr;
            ah[mi] = *(const bf16x8*)&AsH[col * 32 + kg * 8];
            al[mi] = *(const bf16x8*)&AsL[col * 32 + kg * 8];
        }
        #pragma unroll
        for (int ni = 0; ni < 4; ++ni) {
            int col = wq_j * 64 + ni * 16 + fr;
            bh[ni] = *(const bf16x8*)&BsH[col * 32 + kg * 8];
            bl[ni] = *(const bf16x8*)&BsL[col * 32 + kg * 8];
        }
        #pragma unroll
        for (int mi = 0; mi < 4; ++mi)
            #pragma unroll
            for (int ni = 0; ni < 4; ++ni) {
                acc[mi][ni] = __builtin_amdgcn_mfma_f32_16x16x32_bf16(ah[mi], bh[ni], acc[mi][ni], 0, 0, 0);
                acc[mi][ni] = __builtin_amdgcn_mfma_f32_16x16x32_bf16(ah[mi], bl[ni], acc[mi][ni], 0, 0, 0);
                acc[mi][ni] = __builtin_amdgcn_mfma_f32_16x16x32_bf16(al[mi], bh[ni], acc[mi][ni], 0, 0, 0);
            }
        __syncthreads();
    }

    // column reduction: C layout col=lane&15 (j), row=(lane>>4)*4+reg (i)
    int i_base = ib * 128 + wq_i * 64;
    int j_base = jb * 128 + wq_j * 64;
    #pragma unroll
    for (int ni = 0; ni < 4; ++ni) {
        int j = j_base + ni * 16 + fr;
        float bv = -INFINITY; int bi = 0x7fffffff;
        #pragma unroll
        for (int mi = 0; mi < 4; ++mi)
            #pragma unroll
            for (int r = 0; r < 4; ++r) {
                int i = i_base + mi * 16 + kg * 4 + r;
                float v = acc[mi][ni][r];
                if (i < j && v > bv) { bv = v; bi = i; }
            }
        #pragma unroll
        for (int d = 16; d < 64; d <<= 1) {
            float ov = __shfl_xor(bv, d, 64);
            int   oi = __shfl_xor(bi, d, 64);
            if (ov > bv || (ov == bv && oi < bi)) { bv = ov; bi = oi; }
        }
        if (lane < 16) {
            sredv[wq_i * 128 + wq_j * 64 + ni * 16 + lane] = bv;
            sredi[wq_i * 128 + wq_j * 64 + ni * 16 + lane] = bi;
        }
    }
    __syncthreads();
    if (t < 128) {
        float v0 = sredv[t]; int i0 = sredi[t];
        float v1 = sredv[128 + t]; int i1 = sredi[128 + t];
        if (v1 > v0) { v0 = v1; i0 = i1; } // ties keep wq_i=0 (smaller i)
        pmax[(((size_t)n * 32 + ib) << 12) + jb * 128 + t] = v0;
        parg[(((size_t)n * 32 + ib) << 12) + jb * 128 + t] = i0;
    }
}

// ---------------- generic fp32 tiled GEMM (1x1 conv) ----------------
__global__ __launch_bounds__(256) void gemm_dense(
    const float* __restrict__ Wt, const float* __restrict__ bias,
    const float* __restrict__ X0, int c0,
    const float* __restrict__ X1, int c1,
    const float* __restrict__ X2, int c2,
    int Ktot, int Ot,
    const float* __restrict__ gatherP, const int* __restrict__ argIdx,
    int leaky, float* __restrict__ Cout)
{
    __shared__ __align__(16) float As[32][64];
    __shared__ __align__(16) float Bs[32][64];
    int t = threadIdx.x;
    int p0 = blockIdx.x << 6;
    int o0 = blockIdx.y << 6;
    int n = blockIdx.z;
    int tx = t & 15, ty = t >> 4;
    int lw = t & 63, lr = t >> 6;
    float acc[4][4] = {};
    for (int k0 = 0; k0 < Ktot; k0 += 32) {
        #pragma unroll
        for (int l = 0; l < 8; ++l) {
            int kk = lr * 8 + l;
            As[kk][lw] = Wt[(size_t)(k0 + kk) * Ot + o0 + lw];
        }
        #pragma unroll
        for (int l = 0; l < 8; ++l) {
            int kk = lr * 8 + l; int kg = k0 + kk;
            const float* src; int kl, cs;
            if (kg < c0) { src = X0; kl = kg; cs = c0; }
            else if (kg < c0 + c1) { src = X1; kl = kg - c0; cs = c1; }
            else { src = X2; kl = kg - c0 - c1; cs = c2; }
            Bs[kk][lw] = src[((size_t)n * cs + kl) * 4096 + p0 + lw];
        }
        __syncthreads();
        #pragma unroll
        for (int k = 0; k < 32; ++k) {
            float4 av = *(const float4*)&As[k][ty << 2];
            float4 bv = *(const float4*)&Bs[k][tx << 2];
            float a4[4] = {av.x, av.y, av.z, av.w};
            float b4[4] = {bv.x, bv.y, bv.z, bv.w};
            #pragma unroll
            for (int i = 0; i < 4; ++i)
                #pragma unroll
                for (int j2 = 0; j2 < 4; ++j2)
                    acc[i][j2] = fmaf(a4[i], b4[j2], acc[i][j2]);
        }
        __syncthreads();
    }
    #pragma unroll
    for (int i = 0; i < 4; ++i) {
        int o = o0 + (ty << 2) + i;
        float bv = bias ? bias[o] : 0.f;
        #pragma unroll
        for (int j2 = 0; j2 < 4; ++j2) {
            int p = p0 + (tx << 2) + j2;
            float v = acc[i][j2] + bv;
            if (gatherP) {
                int aj = argIdx[(n << 12) + p];
                if (aj >= 0) v += gatherP[((size_t)n * Ot + o) * 4096 + aj];
            }
            if (leaky) v = v > 0.f ? v : 0.2f * v;
            Cout[((size_t)n * Ot + o) * 4096 + p] = v;
        }
    }
}

// ---------------- masked conv as implicit GEMM ----------------
__global__ __launch_bounds__(256) void gemm_conv(
    const float* __restrict__ Wp, const float* __restrict__ bias,
    const float* __restrict__ Y, uint64_t tapenc, int ntaps, int Ot,
    float* __restrict__ Cout)
{
    __shared__ __align__(16) float As[32][64];
    __shared__ __align__(16) float Bs[32][64];
    int t = threadIdx.x;
    int h = blockIdx.x;          // p0 = h*64
    int o0 = blockIdx.y << 6;
    int n = blockIdx.z;
    int tx = t & 15, ty = t >> 4;
    int lw = t & 63, lr = t >> 6;
    int Ktot = ntaps << 7;
    float acc[4][4] = {};
    for (int k0 = 0; k0 < Ktot; k0 += 32) {
        #pragma unroll
        for (int l = 0; l < 8; ++l) {
            int kk = lr * 8 + l;
            As[kk][lw] = Wp[(size_t)(k0 + kk) * Ot + o0 + lw];
        }
        {
            int tp = k0 >> 7;
            int f = (int)((tapenc >> (5 * tp)) & 31);
            int dh = (f & 3) - 2, dw = ((f >> 2) & 7) - 2;
            int r = h + dh; int cw = lw + dw;
            bool okv = (r >= 0) && (r < 64) && (cw >= 0) && (cw < 64);
            #pragma unroll
            for (int l = 0; l < 8; ++l) {
                int kk = lr * 8 + l; int c = (k0 + kk) & 127;
                Bs[kk][lw] = okv ? Y[((size_t)(n * 128 + c) * 64 + r) * 64 + cw] : 0.f;
            }
        }
        __syncthreads();
        #pragma unroll
        for (int k = 0; k < 32; ++k) {
            float4 av = *(const float4*)&As[k][ty << 2];
            float4 bv = *(const float4*)&Bs[k][tx << 2];
            float a4[4] = {av.x, av.y, av.z, av.w};
            float b4[4] = {bv.x, bv.y, bv.z, bv.w};
            #pragma unroll
            for (int i = 0; i < 4; ++i)
                #pragma unroll
                for (int j2 = 0; j2 < 4; ++j2)
                    acc[i][j2] = fmaf(a4[i], b4[j2], acc[i][j2]);
        }
        __syncthreads();
    }
    #pragma unroll
    for (int i = 0; i < 4; ++i) {
        int o = o0 + (ty << 2) + i;
        float bv = bias ? bias[o] : 0.f;
        #pragma unroll
        for (int j2 = 0; j2 < 4; ++j2) {
            int p = (h << 6) + (tx << 2) + j2;
            Cout[((size_t)n * Ot + o) * 4096 + p] = acc[i][j2] + bv;
        }
    }
}

// ---------------- y_prob from para1 ----------------
__global__ __launch_bounds__(256) void yprob_kernel(
    const float* __restrict__ out, const float* __restrict__ y, float* __restrict__ ws)
{
    int idx = blockIdx.x * 256 + threadIdx.x;
    int n = idx >> 12, p = idx & 4095;
    const float* pw = out + OUT_P1 + (size_t)n * 384 * 4096 + p;
    const float* pm = pw + (size_t)128 * 4096;
    const float* psv = pm + (size_t)128 * 4096;
    const float* yy = y + (size_t)n * 128 * 4096 + p;
    float accs = 0.f;
    for (int c = 0; c < 128; ++c) {
        float w  = pw[(size_t)c * 4096];
        float mu = pm[(size_t)c * 4096];
        float ls = psv[(size_t)c * 4096];
        ls = fminf(fmaxf(ls, -7.f), 7.f);
        float tt = (yy[(size_t)c * 4096] - mu) * expf(-ls);
        float lsig = (w >= 0.f) ? -log1pf(expf(-w)) : (w - log1pf(expf(w)));
        float nll = 0.5f * tt * tt + ls + 0.9189385f - lsig;
        accs += expf(-nll);
    }
    ws[WS_YPROB + idx] = accs * (1.0f / 128.0f);
}

// ---------------- merge tile partials, emit S/U/R_arg + gather index + log-sum ----------------
__global__ __launch_bounds__(256) void finalize_kernel(float* __restrict__ ws, float* __restrict__ out)
{
    int idx = blockIdx.x * 256 + threadIdx.x;
    int n = idx >> 12, j = idx & 4095;
    float s, u; int a;
    if (j == 0) { s = 1e-8f; u = 1e-8f; a = -1; }
    else {
        float bv = -INFINITY; int bi = 0x7fffffff;
        const int* pai = (const int*)ws;
        int jbt = j >> 7;
        for (int ib = 0; ib <= jbt; ++ib) {
            float v = ws[WS_PMAX + (((size_t)n * 32 + ib) << 12) + j];
            int ii = pai[WS_PARG + (((size_t)n * 32 + ib) << 12) + j];
            if (v > bv || (v == bv && ii < bi)) { bv = v; bi = ii; }
        }
        s = fminf(fmaxf(bv, 1e-8f), 1.0f);
        if (bi < 0 || bi > 4095) bi = 0;
        float yp = ws[WS_YPROB + ((size_t)n << 12) + bi];
        u = fminf(fmaxf(yp, 1e-8f), 1.0f);
        a = bi;
    }
    out[OUT_S + idx] = s;
    out[OUT_U + idx] = u;
    out[OUT_RA + idx] = (float)a;
    ((int*)ws)[WS_ARGI + idx] = a;
    ws[WS_LSU + idx] = logf(s + 1e-8f) + logf(u + 1e-8f);
}

// ---------------- para2[:,0] += log(S)+log(U) ----------------
__global__ __launch_bounds__(256) void para2add_kernel(float* __restrict__ out, const float* __restrict__ ws)
{
    int idx = blockIdx.x * 256 + threadIdx.x; // N*128*4096
    int p = idx & 4095; int c = (idx >> 12) & 127; int n = idx >> 19;
    out[OUT_P2 + ((size_t)(n * 384 + c) << 12) + p] += ws[WS_LSU + ((size_t)n << 12) + p];
}

// ---------------- launch ----------------
extern "C" void kernel_launch(void* const* d_in, const int* in_sizes, int n_in,
                              void* d_out, int out_size, void* d_ws, size_t ws_size,
                              hipStream_t stream)
{
    const float* y   = (const float*)d_in[0];
    const float* z   = (const float*)d_in[1];
    const float* w5  = (const float*)d_in[2];
    const float* b5  = (const float*)d_in[3];
    const float* w1a = (const float*)d_in[4];
    const float* b1a = (const float*)d_in[5];
    const float* w1b = (const float*)d_in[6];
    const float* b1b = (const float*)d_in[7];
    const float* w1c = (const float*)d_in[8];
    const float* b1c = (const float*)d_in[9];
    const float* wrf = (const float*)d_in[10];
    const float* w2a = (const float*)d_in[11];
    const float* b2a = (const float*)d_in[12];
    const float* w2b = (const float*)d_in[13];
    const float* b2b = (const float*)d_in[14];
    const float* w2c = (const float*)d_in[15];
    const float* b2c = (const float*)d_in[16];
    const float* w3a = (const float*)d_in[17];
    const float* b3a = (const float*)d_in[18];
    const float* w3b = (const float*)d_in[19];
    const float* b3b = (const float*)d_in[20];
    const float* w3c = (const float*)d_in[21];
    const float* b3c = (const float*)d_in[22];
    float* ws  = (float*)d_ws;
    float* out = (float*)d_out;
    const int* argi = (const int*)(ws) + WS_ARGI;

    repack_all<<<3648, 256, 0, stream>>>(w5, wrf, w1a, w1b, w1c, w2a, w2b, w2c, w3a, w3b, w3c, ws);
    sumsq_kernel<<<64, 256, 0, stream>>>(y, ws);
    rnorm_kernel<<<64, 256, 0, stream>>>(ws);
    vbuild_kernel<<<32768, 256, 0, stream>>>(y, ws);
    gram_mfma<<<dim3(528, NB), 256, 0, stream>>>((const ushort_t*)(ws + WS_VH), (const ushort_t*)(ws + WS_VL),
                                                 ws + WS_PMAX, (int*)(ws + WS_PARG));

    // conv5 -> local (overwrites Vt region; gram already done, stream-ordered)
    gemm_conv<<<dim3(64, 4, NB), 256, 0, stream>>>(ws + WS_W5P, b5, y, ENC5, 12, 256, ws + WS_LOCAL);

    // mlp1 -> para1
    gemm_dense<<<dim3(64, 2, NB), 256, 0, stream>>>(ws + WS_W1AT, b1a, ws + WS_LOCAL, 256, nullptr, 0, nullptr, 0,
                                                    256, 128, nullptr, nullptr, 1, ws + WS_HA);
    gemm_dense<<<dim3(64, 2, NB), 256, 0, stream>>>(ws + WS_W1BT, b1b, ws + WS_HA, 128, nullptr, 0, nullptr, 0,
                                                    128, 128, nullptr, nullptr, 1, ws + WS_HB);
    gemm_dense<<<dim3(64, 6, NB), 256, 0, stream>>>(ws + WS_W1CT, b1c, ws + WS_HB, 128, nullptr, 0, nullptr, 0,
                                                    128, 384, nullptr, nullptr, 0, out + OUT_P1);

    yprob_kernel<<<64, 256, 0, stream>>>(out, y, ws);
    finalize_kernel<<<64, 256, 0, stream>>>(ws, out);

    // masked conv3 -> F, then rf projections
    gemm_conv<<<dim3(64, 4, NB), 256, 0, stream>>>(ws + WS_WRP, nullptr, y, ENC3, 5, 256, ws + WS_F);
    gemm_dense<<<dim3(64, 2, NB), 256, 0, stream>>>(ws + WS_W2ATR, nullptr, ws + WS_F, 256, nullptr, 0, nullptr, 0,
                                                    256, 128, nullptr, nullptr, 0, ws + WS_P2);
    gemm_dense<<<dim3(64, 2, NB), 256, 0, stream>>>(ws + WS_W3ATR, nullptr, ws + WS_F, 256, nullptr, 0, nullptr, 0,
                                                    256, 128, nullptr, nullptr, 0, ws + WS_P3);

    // mlp2 -> para2 (+ log terms)
    gemm_dense<<<dim3(64, 2, NB), 256, 0, stream>>>(ws + WS_W2ATL, b2a, ws + WS_LOCAL, 256, nullptr, 0, nullptr, 0,
                                                    256, 128, ws + WS_P2, argi, 1, ws + WS_HA);
    gemm_dense<<<dim3(64, 2, NB), 256, 0, stream>>>(ws + WS_W2BT, b2b, ws + WS_HA, 128, nullptr, 0, nullptr, 0,
                                                    128, 128, nullptr, nullptr, 1, ws + WS_HB);
    gemm_dense<<<dim3(64, 6, NB), 256, 0, stream>>>(ws + WS_W2CT, b2c, ws + WS_HB, 128, nullptr, 0, nullptr, 0,
                                                    128, 384, nullptr, nullptr, 0, out + OUT_P2);
    para2add_kernel<<<8192, 256, 0, stream>>>(out, ws);

    // mlp3 -> para3
    gemm_dense<<<dim3(64, 2, NB), 256, 0, stream>>>(ws + WS_W3ATLZ, b3a, ws + WS_LOCAL, 256, z, 128, nullptr, 0,
                                                    384, 128, ws + WS_P3, argi, 1, ws + WS_HA);
    gemm_dense<<<dim3(64, 2, NB), 256, 0, stream>>>(ws + WS_W3BT, b3b, ws + WS_HA, 128, nullptr, 0, nullptr, 0,
                                                    128, 128, nullptr, nullptr, 1, ws + WS_HB);
    gemm_dense<<<dim3(64, 6, NB), 256, 0, stream>>>(ws + WS_W3CT, b3c, ws + WS_HB, 128, nullptr, 0, nullptr, 0,
                                                    128, 384, nullptr, nullptr, 0, out + OUT_P3);
    (void)in_sizes; (void)n_in; (void)out_size; (void)ws_size;
}

// Round 3
// 680.677 us; speedup vs baseline: 3.5516x; 1.6109x over previous
//
#include <hip/hip_runtime.h>
#include <cstdint>
#include <cstddef>

typedef unsigned short ushort_t;
typedef __attribute__((ext_vector_type(8))) short bf16x8;
typedef __attribute__((ext_vector_type(4))) float f32x4;

#if defined(__has_builtin)
#if __has_builtin(__builtin_amdgcn_global_load_lds)
#define HAVE_GLL 1
#endif
#endif

// ---------------- constants ----------------
constexpr int NB = 4;
// d_out offsets (floats)
constexpr size_t OUT_P1 = 0;
constexpr size_t OUT_P2 = 6291456;
constexpr size_t OUT_P3 = 12582912;
constexpr size_t OUT_S  = 18874368;
constexpr size_t OUT_U  = 18890752;
constexpr size_t OUT_RA = 18907136;

// ---------------- workspace layout (float elements) ----------------
constexpr size_t WS_SS    = 0;
constexpr size_t WS_RNORM = 16384;
constexpr size_t WS_YPROB = 32768;
constexpr size_t WS_ARGI  = 49152;
constexpr size_t WS_LSU   = 65536;
constexpr size_t WS_PMAX  = 81920;    // 524288 (n,32,4096)
constexpr size_t WS_PARG  = 606208;   // 524288 (int)
constexpr size_t WS_WPK   = 1130496;  // 933888 floats = 2x 933888 ushort (h then l)
constexpr size_t WS_BIG   = 2064384;
// V bf16 hi/lo: VH 8388608 ushorts (=4194304 floats), VL same
constexpr size_t WS_VH    = WS_BIG;                  // ushort base
constexpr size_t WS_VL    = WS_BIG + 4194304;
// aliased after gram: localT h/l + FT h/l (each 4194304 ushorts = 2097152 floats)
constexpr size_t WS_LOCH  = WS_BIG;                  // float offsets
constexpr size_t WS_LOCL  = WS_BIG + 2097152;
constexpr size_t WS_FTH   = WS_BIG + 4194304;
constexpr size_t WS_FTL   = WS_BIG + 6291456;
// region B
constexpr size_t WS_HATH  = 10452992; // 2097152 ushorts = 1048576 floats each
constexpr size_t WS_HATL  = 11501568;
constexpr size_t WS_HBTH  = 12550144;
constexpr size_t WS_HBTL  = 13598720;
constexpr size_t WS_P2T   = 14647296; // fp32 [n][4096][128] = 2097152
constexpr size_t WS_P3T   = 16744448; // 2097152 -> end 18841600

// d_out scratch (in OUT_P3 region, dead until mlp3-L3)
constexpr size_t OS_YTPH  = 12582912; // 2367488 ushorts = 1183744 floats
constexpr size_t OS_YTPL  = 13766656;
constexpr size_t OS_ZTPH  = 14950400; // 2097152 ushorts = 1048576 floats
constexpr size_t OS_ZTPL  = 15998976; // end 17047552 < OUT_S

// weight pack sub-offsets (ushort units)
constexpr size_t WP_W5   = 0;        // 256x1536
constexpr size_t WP_WR   = 393216;   // 256x640
constexpr size_t WP_W1A  = 557056;   // 128x256
constexpr size_t WP_W1B  = 589824;   // 128x128
constexpr size_t WP_W1C  = 606208;   // 384x128
constexpr size_t WP_W2AL = 655360;   // 128x256
constexpr size_t WP_W2AR = 688128;   // 128x256
constexpr size_t WP_W2B  = 720896;
constexpr size_t WP_W2C  = 737280;
constexpr size_t WP_W3ALZ= 786432;   // 128x384
constexpr size_t WP_W3AR = 835584;   // 128x256
constexpr size_t WP_W3B  = 868352;
constexpr size_t WP_W3C  = 884736;   // end 933888

// tap encodings: 5 bits per tap: (dh+2) | ((dw+2)<<2)
constexpr uint64_t TENC(int i, int dh, int dw) {
    return ((uint64_t)((dh + 2) | ((dw + 2) << 2))) << (5 * i);
}
constexpr uint64_t ENC5 = TENC(0,-2,-2)|TENC(1,-2,-1)|TENC(2,-2,0)|TENC(3,-2,1)|TENC(4,-2,2)
                        | TENC(5,-1,-2)|TENC(6,-1,-1)|TENC(7,-1,0)|TENC(8,-1,1)|TENC(9,-1,2)
                        | TENC(10,0,-2)|TENC(11,0,-1);
constexpr uint64_t ENC3 = TENC(0,-1,-1)|TENC(1,-1,0)|TENC(2,-1,1)|TENC(3,0,-1)|TENC(4,0,0);

static __device__ inline ushort_t f2bf_rne(float f) {
    uint32_t u = __float_as_uint(f);
    uint32_t r = (u + 0x7fffu + ((u >> 16) & 1u)) >> 16;
    return (ushort_t)r;
}
static __device__ inline float bf2f(ushort_t h) {
    return __uint_as_float(((uint32_t)h) << 16);
}

static __device__ inline void gll16(const ushort_t* g, ushort_t* l) {
#ifdef HAVE_GLL
    __builtin_amdgcn_global_load_lds((const __attribute__((address_space(1))) void*)g,
                                     (__attribute__((address_space(3))) void*)l, 16, 0, 0);
#else
    uint4 v = *(const uint4*)g;
    *(uint4*)((char*)l + (threadIdx.x & 63) * 16) = v;
#endif
}

// ---------------- weight repack + bf16 hi/lo split ----------------
__global__ __launch_bounds__(256) void repack_split(
    const float* __restrict__ w5, const float* __restrict__ wr,
    const float* __restrict__ w1a, const float* __restrict__ w1b, const float* __restrict__ w1c,
    const float* __restrict__ w2a, const float* __restrict__ w2b, const float* __restrict__ w2c,
    const float* __restrict__ w3a, const float* __restrict__ w3b, const float* __restrict__ w3c,
    ushort_t* __restrict__ WH, ushort_t* __restrict__ WL)
{
    int idx = blockIdx.x * 256 + threadIdx.x;
    if (idx >= 933888) return;
    float v; int i = idx;
    if (i < 393216) {
        int o = i / 1536, k = i % 1536; int tp = k >> 7, c = k & 127;
        int f = (int)((ENC5 >> (5 * tp)) & 31); int dh = (f & 3) - 2, dw = ((f >> 2) & 7) - 2;
        v = w5[((size_t)(o * 128 + c)) * 25 + (dh + 2) * 5 + (dw + 2)];
    } else if ((i -= 393216) < 163840) {
        int o = i / 640, k = i % 640; int tp = k >> 7, c = k & 127;
        int f = (int)((ENC3 >> (5 * tp)) & 31); int dh = (f & 3) - 2, dw = ((f >> 2) & 7) - 2;
        v = wr[((size_t)(o * 128 + c)) * 9 + (dh + 1) * 3 + (dw + 1)];
    }
    else if ((i -= 163840) < 32768) v = w1a[i];
    else if ((i -= 32768) < 16384) v = w1b[i];
    else if ((i -= 16384) < 49152) v = w1c[i];
    else if ((i -= 49152) < 32768) { int o = i >> 8, k = i & 255; v = w2a[o * 512 + k]; }
    else if ((i -= 32768) < 32768) { int o = i >> 8, k = i & 255; v = w2a[o * 512 + 256 + k]; }
    else if ((i -= 32768) < 16384) v = w2b[i];
    else if ((i -= 16384) < 49152) v = w2c[i];
    else if ((i -= 49152) < 49152) { int o = i / 384, k = i % 384; v = (k < 256) ? w3a[o * 640 + k] : w3a[o * 640 + 512 + (k - 256)]; }
    else if ((i -= 49152) < 32768) { int o = i >> 8, k = i & 255; v = w3a[o * 640 + 256 + k]; }
    else if ((i -= 32768) < 16384) v = w3b[i];
    else { i -= 16384; v = w3c[i]; }
    ushort_t h = f2bf_rne(v);
    WH[idx] = h;
    WL[idx] = f2bf_rne(v - bf2f(h));
}

// ---------------- zero-fill (uint4 per thread) ----------------
__global__ __launch_bounds__(256) void padclear(float* __restrict__ dst)
{
    size_t i = (size_t)blockIdx.x * 256 + threadIdx.x;
    ((uint4*)dst)[i] = uint4{0u, 0u, 0u, 0u};
}

// ---------------- transpose + bf16 split: [n][128][4096] -> [n][row][128] h/l ----------------
__global__ __launch_bounds__(256) void transsplit(const float* __restrict__ src,
    ushort_t* __restrict__ dh, ushort_t* __restrict__ dl, int pad)
{
    __shared__ float tile[128][17];
    int wc = blockIdx.x, h = blockIdx.y, n = blockIdx.z;
    int t = threadIdx.x;
    {
        int tw = t & 15, tc = t >> 4;
        #pragma unroll
        for (int r = 0; r < 8; ++r) {
            int c = tc * 8 + r;
            tile[c][tw] = src[((size_t)(n * 128 + c) << 12) + (h << 6) + wc * 16 + tw];
        }
    }
    __syncthreads();
    {
        int cc = t & 127, ww = t >> 7;
        #pragma unroll
        for (int r = 0; r < 8; ++r) {
            int w = ww * 8 + r;
            float v = tile[cc][w];
            size_t drow = pad ? ((size_t)n * 4624 + (size_t)(h + 1) * 68 + wc * 16 + w + 1)
                              : ((size_t)n * 4096 + (h << 6) + wc * 16 + w);
            ushort_t hh = f2bf_rne(v);
            dh[drow * 128 + cc] = hh;
            dl[drow * 128 + cc] = f2bf_rne(v - bf2f(hh));
        }
    }
}

// ---------------- per-pixel sum of squares ----------------
__global__ __launch_bounds__(256) void sumsq_kernel(const float* __restrict__ y, float* __restrict__ ws)
{
    int idx = blockIdx.x * 256 + threadIdx.x;
    int n = idx >> 12, p = idx & 4095;
    const float* yp = y + (size_t)n * 128 * 4096 + p;
    float s = 0.f;
    for (int c = 0; c < 128; ++c) { float v = yp[(size_t)c * 4096]; s += v * v; }
    ws[WS_SS + idx] = s;
}

__global__ __launch_bounds__(256) void rnorm_kernel(float* __restrict__ ws)
{
    int idx = blockIdx.x * 256 + threadIdx.x;
    int n = idx >> 12, p = idx & 4095;
    int h = p >> 6, w = p & 63;
    const float* ss = ws + WS_SS + ((size_t)n << 12);
    float nsq = 0.f;
    if (h > 0 && w > 0)  nsq += ss[p - 65];
    if (h > 0)           nsq += ss[p - 64];
    if (h > 0 && w < 63) nsq += ss[p - 63];
    if (w > 0)           nsq += ss[p - 1];
    ws[WS_RNORM + idx] = 1.0f / fmaxf(sqrtf(nsq), 1e-12f);
}

// ---------------- build normalized masked-neighborhood bf16 hi/lo, transposed Vt[n][j][k] ----------------
__global__ __launch_bounds__(256) void vbuild_kernel(const float* __restrict__ y, float* __restrict__ ws)
{
    size_t idx = (size_t)blockIdx.x * 256 + threadIdx.x;
    int k = (int)(idx & 511);
    int j = (int)((idx >> 9) & 4095);
    int n = (int)(idx >> 21);
    int tp = k >> 7, c = k & 127;
    int h = j >> 6, w = j & 63;
    int off = 0; bool ok = false;
    if      (tp == 0) { ok = (h > 0) && (w > 0);  off = -65; }
    else if (tp == 1) { ok = (h > 0);             off = -64; }
    else if (tp == 2) { ok = (h > 0) && (w < 63); off = -63; }
    else              { ok = (w > 0);             off = -1;  }
    float v = 0.f;
    if (ok) v = y[(size_t)(n * 128 + c) * 4096 + j + off] * ws[WS_RNORM + ((size_t)n << 12) + j];
    ushort_t hi = f2bf_rne(v);
    ushort_t lo = f2bf_rne(v - bf2f(hi));
    ((ushort_t*)(ws + WS_VH))[idx] = hi;
    ((ushort_t*)(ws + WS_VL))[idx] = lo;
}

// ---------------- MFMA split-bf16 gram + per-tile column max/argmax ----------------
__global__ __launch_bounds__(256) void gram_mfma(const ushort_t* __restrict__ VH,
                                                 const ushort_t* __restrict__ VL,
                                                 float* __restrict__ pmax, int* __restrict__ parg)
{
    __shared__ __align__(16) ushort_t AsH[128 * 32];
    __shared__ __align__(16) ushort_t AsL[128 * 32];
    __shared__ __align__(16) ushort_t BsH[128 * 32];
    __shared__ __align__(16) ushort_t BsL[128 * 32];
    __shared__ float sredv[256];
    __shared__ int   sredi[256];

    int tb = blockIdx.x, n = blockIdx.y;
    int jb = (int)((sqrtf(8.0f * (float)tb + 1.0f) - 1.0f) * 0.5f);
    while ((jb + 1) * (jb + 2) / 2 <= tb) ++jb;
    while (jb * (jb + 1) / 2 > tb) --jb;
    int ib = tb - jb * (jb + 1) / 2;

    int t = threadIdx.x, lane = t & 63, w = t >> 6;
    int wq_i = w >> 1, wq_j = w & 1;
    int fr = lane & 15, kg = lane >> 4;

    const ushort_t* vhn = VH + ((size_t)n << 21);
    const ushort_t* vln = VL + ((size_t)n << 21);

    int colq = lane >> 2, ks = lane & 3;
    int c0 = (w * 2 + 0) * 16 + colq;
    int c1 = (w * 2 + 1) * 16 + colq;
    size_t sA0 = ((size_t)(ib * 128 + c0)) * 512 + ks * 8;
    size_t sA1 = ((size_t)(ib * 128 + c1)) * 512 + ks * 8;
    size_t sB0 = ((size_t)(jb * 128 + c0)) * 512 + ks * 8;
    size_t sB1 = ((size_t)(jb * 128 + c1)) * 512 + ks * 8;
    int d0 = (w * 2 + 0) * 512;
    int d1 = (w * 2 + 1) * 512;

    f32x4 acc[4][4];
    #pragma unroll
    for (int mi = 0; mi < 4; ++mi)
        #pragma unroll
        for (int ni = 0; ni < 4; ++ni)
            acc[mi][ni] = (f32x4){0.f, 0.f, 0.f, 0.f};

    for (int k0 = 0; k0 < 512; k0 += 32) {
        gll16(vhn + sA0 + k0, &AsH[d0]);
        gll16(vhn + sA1 + k0, &AsH[d1]);
        gll16(vln + sA0 + k0, &AsL[d0]);
        gll16(vln + sA1 + k0, &AsL[d1]);
        gll16(vhn + sB0 + k0, &BsH[d0]);
        gll16(vhn + sB1 + k0, &BsH[d1]);
        gll16(vln + sB0 + k0, &BsL[d0]);
        gll16(vln + sB1 + k0, &BsL[d1]);
#ifdef HAVE_GLL
        asm volatile("s_waitcnt vmcnt(0)" ::: "memory");
#endif
        __syncthreads();

        bf16x8 ah[4], al[4], bh[4], bl[4];
        #pragma unroll
        for (int mi = 0; mi < 4; ++mi) {
            int col = wq_i * 64 + mi * 16 + fr;
            ah[mi] = *(const bf16x8*)&AsH[col * 32 + kg * 8];
            al[mi] = *(const bf16x8*)&AsL[col * 32 + kg * 8];
        }
        #pragma unroll
        for (int ni = 0; ni < 4; ++ni) {
            int col = wq_j * 64 + ni * 16 + fr;
            bh[ni] = *(const bf16x8*)&BsH[col * 32 + kg * 8];
            bl[ni] = *(const bf16x8*)&BsL[col * 32 + kg * 8];
        }
        #pragma unroll
        for (int mi = 0; mi < 4; ++mi)
            #pragma unroll
            for (int ni = 0; ni < 4; ++ni) {
                acc[mi][ni] = __builtin_amdgcn_mfma_f32_16x16x32_bf16(ah[mi], bh[ni], acc[mi][ni], 0, 0, 0);
                acc[mi][ni] = __builtin_amdgcn_mfma_f32_16x16x32_bf16(ah[mi], bl[ni], acc[mi][ni], 0, 0, 0);
                acc[mi][ni] = __builtin_amdgcn_mfma_f32_16x16x32_bf16(al[mi], bh[ni], acc[mi][ni], 0, 0, 0);
            }
        __syncthreads();
    }

    int i_base = ib * 128 + wq_i * 64;
    int j_base = jb * 128 + wq_j * 64;
    #pragma unroll
    for (int ni = 0; ni < 4; ++ni) {
        int j = j_base + ni * 16 + fr;
        float bv = -INFINITY; int bi = 0x7fffffff;
        #pragma unroll
        for (int mi = 0; mi < 4; ++mi)
            #pragma unroll
            for (int r = 0; r < 4; ++r) {
                int i = i_base + mi * 16 + kg * 4 + r;
                float v = acc[mi][ni][r];
                if (i < j && v > bv) { bv = v; bi = i; }
            }
        #pragma unroll
        for (int d = 16; d < 64; d <<= 1) {
            float ov = __shfl_xor(bv, d, 64);
            int   oi = __shfl_xor(bi, d, 64);
            if (ov > bv || (ov == bv && oi < bi)) { bv = ov; bi = oi; }
        }
        if (lane < 16) {
            sredv[wq_i * 128 + wq_j * 64 + ni * 16 + lane] = bv;
            sredi[wq_i * 128 + wq_j * 64 + ni * 16 + lane] = bi;
        }
    }
    __syncthreads();
    if (t < 128) {
        float v0 = sredv[t]; int i0 = sredi[t];
        float v1 = sredv[128 + t]; int i1 = sredi[128 + t];
        if (v1 > v0) { v0 = v1; i0 = i1; }
        pmax[(((size_t)n * 32 + ib) << 12) + jb * 128 + t] = v0;
        parg[(((size_t)n * 32 + ib) << 12) + jb * 128 + t] = i0;
    }
}

// ---------------- MFMA split-bf16 masked conv (implicit GEMM) ----------------
// 128 thr = 2 waves; tile 64 O x 128 P; out bf16 h/l transposed [n][4096][256]
__global__ __launch_bounds__(128) void mfma_conv(
    const ushort_t* __restrict__ WH, const ushort_t* __restrict__ WL, // [256][Ktot]
    const float* __restrict__ bias,
    const ushort_t* __restrict__ YH, const ushort_t* __restrict__ YL, // [n][4624][128]
    uint64_t tapenc, int Ktot,
    ushort_t* __restrict__ outH, ushort_t* __restrict__ outL)
{
    __shared__ __align__(16) ushort_t AsH[64 * 32], AsL[64 * 32];
    __shared__ __align__(16) ushort_t BsH[128 * 32], BsL[128 * 32];
    int t = threadIdx.x, w = t >> 6, lane = t & 63;
    int p0 = blockIdx.x << 7, o0 = blockIdx.y << 6, n = blockIdx.z;
    int colq = lane >> 2, ks = lane & 3;
    int fr = lane & 15, kg = lane >> 4;
    int h0 = p0 >> 6;
    const ushort_t* yh = YH + (size_t)n * 4624 * 128;
    const ushort_t* yl = YL + (size_t)n * 4624 * 128;

    const ushort_t* aSrcH0 = WH + (size_t)(o0 + (2 * w + 0) * 16 + colq) * Ktot + ks * 8;
    const ushort_t* aSrcH1 = WH + (size_t)(o0 + (2 * w + 1) * 16 + colq) * Ktot + ks * 8;
    const ushort_t* aSrcL0 = WL + (size_t)(o0 + (2 * w + 0) * 16 + colq) * Ktot + ks * 8;
    const ushort_t* aSrcL1 = WL + (size_t)(o0 + (2 * w + 1) * 16 + colq) * Ktot + ks * 8;

    f32x4 acc[4][4];
    #pragma unroll
    for (int mi = 0; mi < 4; ++mi)
        #pragma unroll
        for (int ni = 0; ni < 4; ++ni) acc[mi][ni] = (f32x4){0.f, 0.f, 0.f, 0.f};

    for (int k0 = 0; k0 < Ktot; k0 += 32) {
        int tp = k0 >> 7, coff = (k0 & 127) + ks * 8;
        int f = (int)((tapenc >> (5 * tp)) & 31);
        int dh = (f & 3) - 2, dw = ((f >> 2) & 7) - 2;
        gll16(aSrcH0 + k0, &AsH[(2 * w + 0) * 512]);
        gll16(aSrcH1 + k0, &AsH[(2 * w + 1) * 512]);
        gll16(aSrcL0 + k0, &AsL[(2 * w + 0) * 512]);
        gll16(aSrcL1 + k0, &AsL[(2 * w + 1) * 512]);
        #pragma unroll
        for (int cb = 0; cb < 4; ++cb) {
            int c = w * 64 + cb * 16 + colq;
            int prow = (h0 + (c >> 6) + 1 + dh) * 68 + (c & 63) + 1 + dw;
            gll16(yh + (size_t)prow * 128 + coff, &BsH[(w * 4 + cb) * 512]);
            gll16(yl + (size_t)prow * 128 + coff, &BsL[(w * 4 + cb) * 512]);
        }
#ifdef HAVE_GLL
        asm volatile("s_waitcnt vmcnt(0)" ::: "memory");
#endif
        __syncthreads();
        bf16x8 ah[4], al[4], bh[4], bl[4];
        #pragma unroll
        for (int mi = 0; mi < 4; ++mi) {
            int col = mi * 16 + fr;
            ah[mi] = *(const bf16x8*)&AsH[col * 32 + kg * 8];
            al[mi] = *(const bf16x8*)&AsL[col * 32 + kg * 8];
        }
        #pragma unroll
        for (int ni = 0; ni < 4; ++ni) {
            int col = w * 64 + ni * 16 + fr;
            bh[ni] = *(const bf16x8*)&BsH[col * 32 + kg * 8];
            bl[ni] = *(const bf16x8*)&BsL[col * 32 + kg * 8];
        }
        #pragma unroll
        for (int mi = 0; mi < 4; ++mi)
            #pragma unroll
            for (int ni = 0; ni < 4; ++ni) {
                acc[mi][ni] = __builtin_amdgcn_mfma_f32_16x16x32_bf16(ah[mi], bh[ni], acc[mi][ni], 0, 0, 0);
                acc[mi][ni] = __builtin_amdgcn_mfma_f32_16x16x32_bf16(ah[mi], bl[ni], acc[mi][ni], 0, 0, 0);
                acc[mi][ni] = __builtin_amdgcn_mfma_f32_16x16x32_bf16(al[mi], bh[ni], acc[mi][ni], 0, 0, 0);
            }
        __syncthreads();
    }

    #pragma unroll
    for (int mi = 0; mi < 4; ++mi) {
        int og = o0 + mi * 16 + kg * 4;
        f32x4 bv = (f32x4){0.f, 0.f, 0.f, 0.f};
        if (bias) bv = *(const f32x4*)&bias[og];
        #pragma unroll
        for (int ni = 0; ni < 4; ++ni) {
            int p = p0 + w * 64 + ni * 16 + fr;
            f32x4 v = acc[mi][ni] + bv;
            ushort_t h0s = f2bf_rne(v[0]), h1s = f2bf_rne(v[1]), h2s = f2bf_rne(v[2]), h3s = f2bf_rne(v[3]);
            size_t db = (((size_t)n << 12) + p) * 256 + og;
            *(uint2*)&outH[db] = make_uint2(h0s | ((uint32_t)h1s << 16), h2s | ((uint32_t)h3s << 16));
            ushort_t l0s = f2bf_rne(v[0] - bf2f(h0s)), l1s = f2bf_rne(v[1] - bf2f(h1s));
            ushort_t l2s = f2bf_rne(v[2] - bf2f(h2s)), l3s = f2bf_rne(v[3] - bf2f(h3s));
            *(uint2*)&outL[db] = make_uint2(l0s | ((uint32_t)l1s << 16), l2s | ((uint32_t)l3s << 16));
        }
    }
}

// ---------------- MFMA split-bf16 dense 1x1 GEMM ----------------
// 128 thr = 2 waves; tile 64 O x 128 P. B sources k-contiguous [n][4096][str].
// mode 0: f32 [n][Ot][4096]; mode 1: bf16 h/l [n][4096][Ot]; mode 2: f32 [n][4096][128]
__global__ __launch_bounds__(128) void mfma_dense(
    const ushort_t* __restrict__ WH, const ushort_t* __restrict__ WL, // [Ot][Ktot]
    const float* __restrict__ bias,
    const ushort_t* __restrict__ B0H, const ushort_t* __restrict__ B0L, int k0len, int str0,
    const ushort_t* __restrict__ B1H, const ushort_t* __restrict__ B1L, int str1,
    int Ktot, int Ot,
    const float* __restrict__ gatherP, const int* __restrict__ argI,
    int leaky, int mode,
    float* __restrict__ outF, ushort_t* __restrict__ outH, ushort_t* __restrict__ outL)
{
    __shared__ __align__(16) ushort_t AsH[64 * 32], AsL[64 * 32];
    __shared__ __align__(16) ushort_t BsH[128 * 32], BsL[128 * 32];
    int t = threadIdx.x, w = t >> 6, lane = t & 63;
    int p0 = blockIdx.x << 7, o0 = blockIdx.y << 6, n = blockIdx.z;
    int colq = lane >> 2, ks = lane & 3;
    int fr = lane & 15, kg = lane >> 4;

    const ushort_t* aSrcH0 = WH + (size_t)(o0 + (2 * w + 0) * 16 + colq) * Ktot + ks * 8;
    const ushort_t* aSrcH1 = WH + (size_t)(o0 + (2 * w + 1) * 16 + colq) * Ktot + ks * 8;
    const ushort_t* aSrcL0 = WL + (size_t)(o0 + (2 * w + 0) * 16 + colq) * Ktot + ks * 8;
    const ushort_t* aSrcL1 = WL + (size_t)(o0 + (2 * w + 1) * 16 + colq) * Ktot + ks * 8;
    // B row indices for this wave's 4 chunks
    size_t brow[4];
    #pragma unroll
    for (int cb = 0; cb < 4; ++cb)
        brow[cb] = ((size_t)n << 12) + p0 + w * 64 + cb * 16 + colq;

    f32x4 acc[4][4];
    #pragma unroll
    for (int mi = 0; mi < 4; ++mi)
        #pragma unroll
        for (int ni = 0; ni < 4; ++ni) acc[mi][ni] = (f32x4){0.f, 0.f, 0.f, 0.f};

    for (int k0 = 0; k0 < Ktot; k0 += 32) {
        gll16(aSrcH0 + k0, &AsH[(2 * w + 0) * 512]);
        gll16(aSrcH1 + k0, &AsH[(2 * w + 1) * 512]);
        gll16(aSrcL0 + k0, &AsL[(2 * w + 0) * 512]);
        gll16(aSrcL1 + k0, &AsL[(2 * w + 1) * 512]);
        const ushort_t* bh_; const ushort_t* bl_; int kk; int str;
        if (k0 < k0len) { bh_ = B0H; bl_ = B0L; kk = k0; str = str0; }
        else            { bh_ = B1H; bl_ = B1L; kk = k0 - k0len; str = str1; }
        kk += ks * 8;
        #pragma unroll
        for (int cb = 0; cb < 4; ++cb) {
            gll16(bh_ + brow[cb] * str + kk, &BsH[(w * 4 + cb) * 512]);
            gll16(bl_ + brow[cb] * str + kk, &BsL[(w * 4 + cb) * 512]);
        }
#ifdef HAVE_GLL
        asm volatile("s_waitcnt vmcnt(0)" ::: "memory");
#endif
        __syncthreads();
        bf16x8 ah[4], al[4], bh[4], bl[4];
        #pragma unroll
        for (int mi = 0; mi < 4; ++mi) {
            int col = mi * 16 + fr;
            ah[mi] = *(const bf16x8*)&AsH[col * 32 + kg * 8];
            al[mi] = *(const bf16x8*)&AsL[col * 32 + kg * 8];
        }
        #pragma unroll
        for (int ni = 0; ni < 4; ++ni) {
            int col = w * 64 + ni * 16 + fr;
            bh[ni] = *(const bf16x8*)&BsH[col * 32 + kg * 8];
            bl[ni] = *(const bf16x8*)&BsL[col * 32 + kg * 8];
        }
        #pragma unroll
        for (int mi = 0; mi < 4; ++mi)
            #pragma unroll
            for (int ni = 0; ni < 4; ++ni) {
                acc[mi][ni] = __builtin_amdgcn_mfma_f32_16x16x32_bf16(ah[mi], bh[ni], acc[mi][ni], 0, 0, 0);
                acc[mi][ni] = __builtin_amdgcn_mfma_f32_16x16x32_bf16(ah[mi], bl[ni], acc[mi][ni], 0, 0, 0);
                acc[mi][ni] = __builtin_amdgcn_mfma_f32_16x16x32_bf16(al[mi], bh[ni], acc[mi][ni], 0, 0, 0);
            }
        __syncthreads();
    }

    #pragma unroll
    for (int mi = 0; mi < 4; ++mi) {
        int og = o0 + mi * 16 + kg * 4;
        f32x4 bv = (f32x4){0.f, 0.f, 0.f, 0.f};
        if (bias) bv = *(const f32x4*)&bias[og];
        #pragma unroll
        for (int ni = 0; ni < 4; ++ni) {
            int p = p0 + w * 64 + ni * 16 + fr;
            f32x4 v = acc[mi][ni] + bv;
            if (gatherP) {
                int aj = argI[(n << 12) + p];
                if (aj >= 0) v += *(const f32x4*)&gatherP[(((size_t)n << 12) + aj) * 128 + og];
            }
            if (leaky) {
                #pragma unroll
                for (int r = 0; r < 4; ++r) v[r] = v[r] > 0.f ? v[r] : 0.2f * v[r];
            }
            if (mode == 0) {
                float* dst = outF + ((size_t)(n * Ot + og) << 12) + p;
                dst[0] = v[0]; dst[4096] = v[1]; dst[8192] = v[2]; dst[12288] = v[3];
            } else if (mode == 2) {
                *(f32x4*)&outF[(((size_t)n << 12) + p) * 128 + og] = v;
            } else {
                ushort_t h0s = f2bf_rne(v[0]), h1s = f2bf_rne(v[1]), h2s = f2bf_rne(v[2]), h3s = f2bf_rne(v[3]);
                size_t db = (((size_t)n << 12) + p) * Ot + og;
                *(uint2*)&outH[db] = make_uint2(h0s | ((uint32_t)h1s << 16), h2s | ((uint32_t)h3s << 16));
                ushort_t l0s = f2bf_rne(v[0] - bf2f(h0s)), l1s = f2bf_rne(v[1] - bf2f(h1s));
                ushort_t l2s = f2bf_rne(v[2] - bf2f(h2s)), l3s = f2bf_rne(v[3] - bf2f(h3s));
                *(uint2*)&outL[db] = make_uint2(l0s | ((uint32_t)l1s << 16), l2s | ((uint32_t)l3s << 16));
            }
        }
    }
}

// ---------------- y_prob from para1 ----------------
__global__ __launch_bounds__(256) void yprob_kernel(
    const float* __restrict__ out, const float* __restrict__ y, float* __restrict__ ws)
{
    int idx = blockIdx.x * 256 + threadIdx.x;
    int n = idx >> 12, p = idx & 4095;
    const float* pw = out + OUT_P1 + (size_t)n * 384 * 4096 + p;
    const float* pm = pw + (size_t)128 * 4096;
    const float* psv = pm + (size_t)128 * 4096;
    const float* yy = y + (size_t)n * 128 * 4096 + p;
    float accs = 0.f;
    for (int c = 0; c < 128; ++c) {
        float w  = pw[(size_t)c * 4096];
        float mu = pm[(size_t)c * 4096];
        float ls = psv[(size_t)c * 4096];
        ls = fminf(fmaxf(ls, -7.f), 7.f);
        float tt = (yy[(size_t)c * 4096] - mu) * expf(-ls);
        float lsig = (w >= 0.f) ? -log1pf(expf(-w)) : (w - log1pf(expf(w)));
        float nll = 0.5f * tt * tt + ls + 0.9189385f - lsig;
        accs += expf(-nll);
    }
    ws[WS_YPROB + idx] = accs * (1.0f / 128.0f);
}

// ---------------- merge tile partials, emit S/U/R_arg ----------------
__global__ __launch_bounds__(256) void finalize_kernel(float* __restrict__ ws, float* __restrict__ out)
{
    int idx = blockIdx.x * 256 + threadIdx.x;
    int n = idx >> 12, j = idx & 4095;
    float s, u; int a;
    if (j == 0) { s = 1e-8f; u = 1e-8f; a = -1; }
    else {
        float bv = -INFINITY; int bi = 0x7fffffff;
        const int* pai = (const int*)ws;
        int jbt = j >> 7;
        for (int ib = 0; ib <= jbt; ++ib) {
            float v = ws[WS_PMAX + (((size_t)n * 32 + ib) << 12) + j];
            int ii = pai[WS_PARG + (((size_t)n * 32 + ib) << 12) + j];
            if (v > bv || (v == bv && ii < bi)) { bv = v; bi = ii; }
        }
        s = fminf(fmaxf(bv, 1e-8f), 1.0f);
        if (bi < 0 || bi > 4095) bi = 0;
        float yp = ws[WS_YPROB + ((size_t)n << 12) + bi];
        u = fminf(fmaxf(yp, 1e-8f), 1.0f);
        a = bi;
    }
    out[OUT_S + idx] = s;
    out[OUT_U + idx] = u;
    out[OUT_RA + idx] = (float)a;
    ((int*)ws)[WS_ARGI + idx] = a;
    ws[WS_LSU + idx] = logf(s + 1e-8f) + logf(u + 1e-8f);
}

// ---------------- para2[:,0] += log(S)+log(U) ----------------
__global__ __launch_bounds__(256) void para2add_kernel(float* __restrict__ out, const float* __restrict__ ws)
{
    int idx = blockIdx.x * 256 + threadIdx.x;
    int p = idx & 4095; int c = (idx >> 12) & 127; int n = idx >> 19;
    out[OUT_P2 + ((size_t)(n * 384 + c) << 12) + p] += ws[WS_LSU + ((size_t)n << 12) + p];
}

// ---------------- launch ----------------
extern "C" void kernel_launch(void* const* d_in, const int* in_sizes, int n_in,
                              void* d_out, int out_size, void* d_ws, size_t ws_size,
                              hipStream_t stream)
{
    const float* y   = (const float*)d_in[0];
    const float* z   = (const float*)d_in[1];
    const float* w5  = (const float*)d_in[2];
    const float* b5  = (const float*)d_in[3];
    const float* w1a = (const float*)d_in[4];
    const float* b1a = (const float*)d_in[5];
    const float* w1b = (const float*)d_in[6];
    const float* b1b = (const float*)d_in[7];
    const float* w1c = (const float*)d_in[8];
    const float* b1c = (const float*)d_in[9];
    const float* wrf = (const float*)d_in[10];
    const float* w2a = (const float*)d_in[11];
    const float* b2a = (const float*)d_in[12];
    const float* w2b = (const float*)d_in[13];
    const float* b2b = (const float*)d_in[14];
    const float* w2c = (const float*)d_in[15];
    const float* b2c = (const float*)d_in[16];
    const float* w3a = (const float*)d_in[17];
    const float* b3a = (const float*)d_in[18];
    const float* w3b = (const float*)d_in[19];
    const float* b3b = (const float*)d_in[20];
    const float* w3c = (const float*)d_in[21];
    const float* b3c = (const float*)d_in[22];
    float* ws  = (float*)d_ws;
    float* out = (float*)d_out;
    const int* argi = (const int*)(ws) + WS_ARGI;

    ushort_t* wph = (ushort_t*)(ws + WS_WPK);
    ushort_t* wpl = wph + 933888;
    ushort_t* locH = (ushort_t*)(ws + WS_LOCH);
    ushort_t* locL = (ushort_t*)(ws + WS_LOCL);
    ushort_t* ftH  = (ushort_t*)(ws + WS_FTH);
    ushort_t* ftL  = (ushort_t*)(ws + WS_FTL);
    ushort_t* haH  = (ushort_t*)(ws + WS_HATH);
    ushort_t* haL  = (ushort_t*)(ws + WS_HATL);
    ushort_t* hbH  = (ushort_t*)(ws + WS_HBTH);
    ushort_t* hbL  = (ushort_t*)(ws + WS_HBTL);
    float* p2t = ws + WS_P2T;
    float* p3t = ws + WS_P3T;
    ushort_t* ytpH = (ushort_t*)(out + OS_YTPH);
    ushort_t* ytpL = (ushort_t*)(out + OS_YTPL);
    ushort_t* ztpH = (ushort_t*)(out + OS_ZTPH);
    ushort_t* ztpL = (ushort_t*)(out + OS_ZTPL);

    repack_split<<<3648, 256, 0, stream>>>(w5, wrf, w1a, w1b, w1c, w2a, w2b, w2c, w3a, w3b, w3c, wph, wpl);
    padclear<<<2312, 256, 0, stream>>>(out + OS_YTPH);
    transsplit<<<dim3(4, 64, NB), 256, 0, stream>>>(y, ytpH, ytpL, 1);
    transsplit<<<dim3(4, 64, NB), 256, 0, stream>>>(z, ztpH, ztpL, 0);
    sumsq_kernel<<<64, 256, 0, stream>>>(y, ws);
    rnorm_kernel<<<64, 256, 0, stream>>>(ws);
    vbuild_kernel<<<32768, 256, 0, stream>>>(y, ws);
    gram_mfma<<<dim3(528, NB), 256, 0, stream>>>((const ushort_t*)(ws + WS_VH), (const ushort_t*)(ws + WS_VL),
                                                 ws + WS_PMAX, (int*)(ws + WS_PARG));

    // conv5 -> localT (overwrites V; gram done, stream-ordered)
    mfma_conv<<<dim3(32, 4, NB), 128, 0, stream>>>(wph + WP_W5, wpl + WP_W5, b5, ytpH, ytpL, ENC5, 1536, locH, locL);
    // conv3 -> FT
    mfma_conv<<<dim3(32, 4, NB), 128, 0, stream>>>(wph + WP_WR, wpl + WP_WR, nullptr, ytpH, ytpL, ENC3, 640, ftH, ftL);
    // rf projections -> P2T/P3T (f32 transposed)
    mfma_dense<<<dim3(32, 2, NB), 128, 0, stream>>>(wph + WP_W2AR, wpl + WP_W2AR, nullptr,
        ftH, ftL, 256, 256, nullptr, nullptr, 0, 256, 128, nullptr, nullptr, 0, 2, p2t, nullptr, nullptr);
    mfma_dense<<<dim3(32, 2, NB), 128, 0, stream>>>(wph + WP_W3AR, wpl + WP_W3AR, nullptr,
        ftH, ftL, 256, 256, nullptr, nullptr, 0, 256, 128, nullptr, nullptr, 0, 2, p3t, nullptr, nullptr);

    // mlp1
    mfma_dense<<<dim3(32, 2, NB), 128, 0, stream>>>(wph + WP_W1A, wpl + WP_W1A, b1a,
        locH, locL, 256, 256, nullptr, nullptr, 0, 256, 128, nullptr, nullptr, 1, 1, nullptr, haH, haL);
    mfma_dense<<<dim3(32, 2, NB), 128, 0, stream>>>(wph + WP_W1B, wpl + WP_W1B, b1b,
        haH, haL, 128, 128, nullptr, nullptr, 0, 128, 128, nullptr, nullptr, 1, 1, nullptr, hbH, hbL);
    mfma_dense<<<dim3(32, 6, NB), 128, 0, stream>>>(wph + WP_W1C, wpl + WP_W1C, b1c,
        hbH, hbL, 128, 128, nullptr, nullptr, 0, 128, 384, nullptr, nullptr, 0, 0, out + OUT_P1, nullptr, nullptr);

    yprob_kernel<<<64, 256, 0, stream>>>(out, y, ws);
    finalize_kernel<<<64, 256, 0, stream>>>(ws, out);

    // mlp2 (+gather P2T)
    mfma_dense<<<dim3(32, 2, NB), 128, 0, stream>>>(wph + WP_W2AL, wpl + WP_W2AL, b2a,
        locH, locL, 256, 256, nullptr, nullptr, 0, 256, 128, p2t, argi, 1, 1, nullptr, haH, haL);
    mfma_dense<<<dim3(32, 2, NB), 128, 0, stream>>>(wph + WP_W2B, wpl + WP_W2B, b2b,
        haH, haL, 128, 128, nullptr, nullptr, 0, 128, 128, nullptr, nullptr, 1, 1, nullptr, hbH, hbL);
    mfma_dense<<<dim3(32, 6, NB), 128, 0, stream>>>(wph + WP_W2C, wpl + WP_W2C, b2c,
        hbH, hbL, 128, 128, nullptr, nullptr, 0, 128, 384, nullptr, nullptr, 0, 0, out + OUT_P2, nullptr, nullptr);
    para2add_kernel<<<8192, 256, 0, stream>>>(out, ws);

    // mlp3 (+z rows, gather P3T)
    mfma_dense<<<dim3(32, 2, NB), 128, 0, stream>>>(wph + WP_W3ALZ, wpl + WP_W3ALZ, b3a,
        locH, locL, 256, 256, ztpH, ztpL, 128, 384, 128, p3t, argi, 1, 1, nullptr, haH, haL);
    mfma_dense<<<dim3(32, 2, NB), 128, 0, stream>>>(wph + WP_W3B, wpl + WP_W3B, b3b,
        haH, haL, 128, 128, nullptr, nullptr, 0, 128, 128, nullptr, nullptr, 1, 1, nullptr, hbH, hbL);
    mfma_dense<<<dim3(32, 6, NB), 128, 0, stream>>>(wph + WP_W3C, wpl + WP_W3C, b3c,
        hbH, hbL, 128, 128, nullptr, nullptr, 0, 128, 384, nullptr, nullptr, 0, 0, out + OUT_P3, nullptr, nullptr);
    (void)in_sizes; (void)n_in; (void)out_size; (void)ws_size;
}

// Round 4
// 623.386 us; speedup vs baseline: 3.8780x; 1.0919x over previous
//
#include <hip/hip_runtime.h>
#include <cstdint>
#include <cstddef>

typedef unsigned short ushort_t;
typedef __attribute__((ext_vector_type(8))) short bf16x8;
typedef __attribute__((ext_vector_type(4))) float f32x4;

#if defined(__has_builtin)
#if __has_builtin(__builtin_amdgcn_global_load_lds)
#define HAVE_GLL 1
#endif
#endif

// ---------------- constants ----------------
constexpr int NB = 4;
// d_out offsets (floats)
constexpr size_t OUT_P1 = 0;
constexpr size_t OUT_P2 = 6291456;
constexpr size_t OUT_P3 = 12582912;
constexpr size_t OUT_S  = 18874368;
constexpr size_t OUT_U  = 18890752;
constexpr size_t OUT_RA = 18907136;

// ---------------- workspace layout (float elements) ----------------
constexpr size_t WS_SS    = 0;
constexpr size_t WS_RNORM = 16384;
constexpr size_t WS_YPROB = 32768;
constexpr size_t WS_ARGI  = 49152;
constexpr size_t WS_LSU   = 65536;
constexpr size_t WS_PMAX  = 81920;    // 524288 (n,32,4096)
constexpr size_t WS_PARG  = 606208;   // 524288 (int)
constexpr size_t WS_WPK   = 1130496;  // 933888 floats = 2x 933888 ushort (h then l)
constexpr size_t WS_BIG   = 2064384;
// V bf16 hi/lo: VH 8388608 ushorts (=4194304 floats), VL same
constexpr size_t WS_VH    = WS_BIG;
constexpr size_t WS_VL    = WS_BIG + 4194304;
// aliased after gram: localT h/l + FT h/l
constexpr size_t WS_LOCH  = WS_BIG;
constexpr size_t WS_LOCL  = WS_BIG + 2097152;
constexpr size_t WS_FTH   = WS_BIG + 4194304;
constexpr size_t WS_FTL   = WS_BIG + 6291456;
// after V freed:
constexpr size_t WS_P2T   = 10452992; // fp32 [n][4096][128] = 2097152
constexpr size_t WS_P3T   = 12550144; // 2097152
constexpr size_t WS_ZTPH  = 14647296; // 2097152 ushorts = 1048576 floats
constexpr size_t WS_ZTPL  = 15695872; // end 16744448

// d_out scratch (in OUT_P3 region; read only by convs, which finish before
// mlp_fused(mlp3) writes OUT_P3)
constexpr size_t OS_YTPH  = 12582912; // 2367488 ushorts = 1183744 floats
constexpr size_t OS_YTPL  = 13766656; // end 14950400 < OUT_S

// weight pack sub-offsets (ushort units)
constexpr size_t WP_W5   = 0;        // 256x1536
constexpr size_t WP_WR   = 393216;   // 256x640
constexpr size_t WP_W1A  = 557056;   // 128x256
constexpr size_t WP_W1B  = 589824;   // 128x128
constexpr size_t WP_W1C  = 606208;   // 384x128
constexpr size_t WP_W2AL = 655360;   // 128x256
constexpr size_t WP_W2AR = 688128;   // 128x256
constexpr size_t WP_W2B  = 720896;
constexpr size_t WP_W2C  = 737280;
constexpr size_t WP_W3ALZ= 786432;   // 128x384
constexpr size_t WP_W3AR = 835584;   // 128x256
constexpr size_t WP_W3B  = 868352;
constexpr size_t WP_W3C  = 884736;   // end 933888

// tap encodings: 5 bits per tap: (dh+2) | ((dw+2)<<2)
constexpr uint64_t TENC(int i, int dh, int dw) {
    return ((uint64_t)((dh + 2) | ((dw + 2) << 2))) << (5 * i);
}
constexpr uint64_t ENC5 = TENC(0,-2,-2)|TENC(1,-2,-1)|TENC(2,-2,0)|TENC(3,-2,1)|TENC(4,-2,2)
                        | TENC(5,-1,-2)|TENC(6,-1,-1)|TENC(7,-1,0)|TENC(8,-1,1)|TENC(9,-1,2)
                        | TENC(10,0,-2)|TENC(11,0,-1);
constexpr uint64_t ENC3 = TENC(0,-1,-1)|TENC(1,-1,0)|TENC(2,-1,1)|TENC(3,0,-1)|TENC(4,0,0);

static __device__ inline ushort_t f2bf_rne(float f) {
    uint32_t u = __float_as_uint(f);
    uint32_t r = (u + 0x7fffu + ((u >> 16) & 1u)) >> 16;
    return (ushort_t)r;
}
static __device__ inline float bf2f(ushort_t h) {
    return __uint_as_float(((uint32_t)h) << 16);
}

static __device__ inline void gll16(const ushort_t* g, ushort_t* l) {
#ifdef HAVE_GLL
    __builtin_amdgcn_global_load_lds((const __attribute__((address_space(1))) void*)g,
                                     (__attribute__((address_space(3))) void*)l, 16, 0, 0);
#else
    uint4 v = *(const uint4*)g;
    *(uint4*)((char*)l + (threadIdx.x & 63) * 16) = v;
#endif
}

#define MFMA3(AH, AL, BH, BL, ACC) \
    ACC = __builtin_amdgcn_mfma_f32_16x16x32_bf16(AH, BH, ACC, 0, 0, 0); \
    ACC = __builtin_amdgcn_mfma_f32_16x16x32_bf16(AH, BL, ACC, 0, 0, 0); \
    ACC = __builtin_amdgcn_mfma_f32_16x16x32_bf16(AL, BH, ACC, 0, 0, 0);

// ---------------- weight repack + bf16 hi/lo split ----------------
__global__ __launch_bounds__(256) void repack_split(
    const float* __restrict__ w5, const float* __restrict__ wr,
    const float* __restrict__ w1a, const float* __restrict__ w1b, const float* __restrict__ w1c,
    const float* __restrict__ w2a, const float* __restrict__ w2b, const float* __restrict__ w2c,
    const float* __restrict__ w3a, const float* __restrict__ w3b, const float* __restrict__ w3c,
    ushort_t* __restrict__ WH, ushort_t* __restrict__ WL)
{
    int idx = blockIdx.x * 256 + threadIdx.x;
    if (idx >= 933888) return;
    float v; int i = idx;
    if (i < 393216) {
        int o = i / 1536, k = i % 1536; int tp = k >> 7, c = k & 127;
        int f = (int)((ENC5 >> (5 * tp)) & 31); int dh = (f & 3) - 2, dw = ((f >> 2) & 7) - 2;
        v = w5[((size_t)(o * 128 + c)) * 25 + (dh + 2) * 5 + (dw + 2)];
    } else if ((i -= 393216) < 163840) {
        int o = i / 640, k = i % 640; int tp = k >> 7, c = k & 127;
        int f = (int)((ENC3 >> (5 * tp)) & 31); int dh = (f & 3) - 2, dw = ((f >> 2) & 7) - 2;
        v = wr[((size_t)(o * 128 + c)) * 9 + (dh + 1) * 3 + (dw + 1)];
    }
    else if ((i -= 163840) < 32768) v = w1a[i];
    else if ((i -= 32768) < 16384) v = w1b[i];
    else if ((i -= 16384) < 49152) v = w1c[i];
    else if ((i -= 49152) < 32768) { int o = i >> 8, k = i & 255; v = w2a[o * 512 + k]; }
    else if ((i -= 32768) < 32768) { int o = i >> 8, k = i & 255; v = w2a[o * 512 + 256 + k]; }
    else if ((i -= 32768) < 16384) v = w2b[i];
    else if ((i -= 16384) < 49152) v = w2c[i];
    else if ((i -= 49152) < 49152) { int o = i / 384, k = i % 384; v = (k < 256) ? w3a[o * 640 + k] : w3a[o * 640 + 512 + (k - 256)]; }
    else if ((i -= 49152) < 32768) { int o = i >> 8, k = i & 255; v = w3a[o * 640 + 256 + k]; }
    else if ((i -= 32768) < 16384) v = w3b[i];
    else { i -= 16384; v = w3c[i]; }
    ushort_t h = f2bf_rne(v);
    WH[idx] = h;
    WL[idx] = f2bf_rne(v - bf2f(h));
}

// ---------------- zero-fill (uint4 per thread) ----------------
__global__ __launch_bounds__(256) void padclear(float* __restrict__ dst)
{
    size_t i = (size_t)blockIdx.x * 256 + threadIdx.x;
    ((uint4*)dst)[i] = uint4{0u, 0u, 0u, 0u};
}

// ---------------- transpose + bf16 split: [n][128][4096] -> [n][row][128] h/l ----------------
__global__ __launch_bounds__(256) void transsplit(const float* __restrict__ src,
    ushort_t* __restrict__ dh, ushort_t* __restrict__ dl, int pad)
{
    __shared__ float tile[128][17];
    int wc = blockIdx.x, h = blockIdx.y, n = blockIdx.z;
    int t = threadIdx.x;
    {
        int tw = t & 15, tc = t >> 4;
        #pragma unroll
        for (int r = 0; r < 8; ++r) {
            int c = tc * 8 + r;
            tile[c][tw] = src[((size_t)(n * 128 + c) << 12) + (h << 6) + wc * 16 + tw];
        }
    }
    __syncthreads();
    {
        int cc = t & 127, ww = t >> 7;
        #pragma unroll
        for (int r = 0; r < 8; ++r) {
            int w = ww * 8 + r;
            float v = tile[cc][w];
            size_t drow = pad ? ((size_t)n * 4624 + (size_t)(h + 1) * 68 + wc * 16 + w + 1)
                              : ((size_t)n * 4096 + (h << 6) + wc * 16 + w);
            ushort_t hh = f2bf_rne(v);
            dh[drow * 128 + cc] = hh;
            dl[drow * 128 + cc] = f2bf_rne(v - bf2f(hh));
        }
    }
}

// ---------------- per-pixel sum of squares ----------------
__global__ __launch_bounds__(256) void sumsq_kernel(const float* __restrict__ y, float* __restrict__ ws)
{
    int idx = blockIdx.x * 256 + threadIdx.x;
    int n = idx >> 12, p = idx & 4095;
    const float* yp = y + (size_t)n * 128 * 4096 + p;
    float s = 0.f;
    for (int c = 0; c < 128; ++c) { float v = yp[(size_t)c * 4096]; s += v * v; }
    ws[WS_SS + idx] = s;
}

__global__ __launch_bounds__(256) void rnorm_kernel(float* __restrict__ ws)
{
    int idx = blockIdx.x * 256 + threadIdx.x;
    int n = idx >> 12, p = idx & 4095;
    int h = p >> 6, w = p & 63;
    const float* ss = ws + WS_SS + ((size_t)n << 12);
    float nsq = 0.f;
    if (h > 0 && w > 0)  nsq += ss[p - 65];
    if (h > 0)           nsq += ss[p - 64];
    if (h > 0 && w < 63) nsq += ss[p - 63];
    if (w > 0)           nsq += ss[p - 1];
    ws[WS_RNORM + idx] = 1.0f / fmaxf(sqrtf(nsq), 1e-12f);
}

// ---------------- build normalized masked-neighborhood bf16 hi/lo, transposed Vt[n][j][k] ----------------
// reads padded transposed ytp (coalesced; pad ring supplies zeros)
__global__ __launch_bounds__(256) void vbuild_kernel(const ushort_t* __restrict__ ytpH,
                                                     const ushort_t* __restrict__ ytpL,
                                                     float* __restrict__ ws)
{
    size_t idx = (size_t)blockIdx.x * 256 + threadIdx.x; // (n*4096 + j)*512 + k
    int k = (int)(idx & 511);
    int j = (int)((idx >> 12) & 4095);
    int kj = (int)((idx >> 9) & 7);      // unused split helper
    (void)kj;
    j = (int)((idx >> 9) & 4095);
    int n = (int)(idx >> 21);
    int tp = k >> 7, c = k & 127;
    int h = j >> 6, w = j & 63;
    int dh, dw;
    if      (tp == 0) { dh = -1; dw = -1; }
    else if (tp == 1) { dh = -1; dw = 0;  }
    else if (tp == 2) { dh = -1; dw = 1;  }
    else              { dh = 0;  dw = -1; }
    size_t row = (size_t)n * 4624 + (size_t)(h + 1 + dh) * 68 + (w + 1 + dw);
    float v = (bf2f(ytpH[row * 128 + c]) + bf2f(ytpL[row * 128 + c]))
              * ws[WS_RNORM + ((size_t)n << 12) + j];
    ushort_t hi = f2bf_rne(v);
    ushort_t lo = f2bf_rne(v - bf2f(hi));
    ((ushort_t*)(ws + WS_VH))[idx] = hi;
    ((ushort_t*)(ws + WS_VL))[idx] = lo;
}

// ---------------- MFMA split-bf16 gram + per-tile column max/argmax ----------------
__global__ __launch_bounds__(256) void gram_mfma(const ushort_t* __restrict__ VH,
                                                 const ushort_t* __restrict__ VL,
                                                 float* __restrict__ pmax, int* __restrict__ parg)
{
    __shared__ __align__(16) ushort_t AsH[128 * 32];
    __shared__ __align__(16) ushort_t AsL[128 * 32];
    __shared__ __align__(16) ushort_t BsH[128 * 32];
    __shared__ __align__(16) ushort_t BsL[128 * 32];
    __shared__ float sredv[256];
    __shared__ int   sredi[256];

    // XCD-aware bijective remap: 528 = 8 * 66; consecutive logical tiles
    // (same jb panel) land on the same XCD for L2 reuse.
    int bx = blockIdx.x;
    int tb = (bx & 7) * 66 + (bx >> 3);
    int n = blockIdx.y;
    int jb = (int)((sqrtf(8.0f * (float)tb + 1.0f) - 1.0f) * 0.5f);
    while ((jb + 1) * (jb + 2) / 2 <= tb) ++jb;
    while (jb * (jb + 1) / 2 > tb) --jb;
    int ib = tb - jb * (jb + 1) / 2;

    int t = threadIdx.x, lane = t & 63, w = t >> 6;
    int wq_i = w >> 1, wq_j = w & 1;
    int fr = lane & 15, kg = lane >> 4;

    const ushort_t* vhn = VH + ((size_t)n << 21);
    const ushort_t* vln = VL + ((size_t)n << 21);

    int colq = lane >> 2, ks = lane & 3;
    int c0 = (w * 2 + 0) * 16 + colq;
    int c1 = (w * 2 + 1) * 16 + colq;
    size_t sA0 = ((size_t)(ib * 128 + c0)) * 512 + ks * 8;
    size_t sA1 = ((size_t)(ib * 128 + c1)) * 512 + ks * 8;
    size_t sB0 = ((size_t)(jb * 128 + c0)) * 512 + ks * 8;
    size_t sB1 = ((size_t)(jb * 128 + c1)) * 512 + ks * 8;
    int d0 = (w * 2 + 0) * 512;
    int d1 = (w * 2 + 1) * 512;

    f32x4 acc[4][4];
    #pragma unroll
    for (int mi = 0; mi < 4; ++mi)
        #pragma unroll
        for (int ni = 0; ni < 4; ++ni)
            acc[mi][ni] = (f32x4){0.f, 0.f, 0.f, 0.f};

    for (int k0 = 0; k0 < 512; k0 += 32) {
        gll16(vhn + sA0 + k0, &AsH[d0]);
        gll16(vhn + sA1 + k0, &AsH[d1]);
        gll16(vln + sA0 + k0, &AsL[d0]);
        gll16(vln + sA1 + k0, &AsL[d1]);
        gll16(vhn + sB0 + k0, &BsH[d0]);
        gll16(vhn + sB1 + k0, &BsH[d1]);
        gll16(vln + sB0 + k0, &BsL[d0]);
        gll16(vln + sB1 + k0, &BsL[d1]);
#ifdef HAVE_GLL
        asm volatile("s_waitcnt vmcnt(0)" ::: "memory");
#endif
        __syncthreads();

        bf16x8 ah[4], al[4], bh[4], bl[4];
        #pragma unroll
        for (int mi = 0; mi < 4; ++mi) {
            int col = wq_i * 64 + mi * 16 + fr;
            ah[mi] = *(const bf16x8*)&AsH[col * 32 + kg * 8];
            al[mi] = *(const bf16x8*)&AsL[col * 32 + kg * 8];
        }
        #pragma unroll
        for (int ni = 0; ni < 4; ++ni) {
            int col = wq_j * 64 + ni * 16 + fr;
            bh[ni] = *(const bf16x8*)&BsH[col * 32 + kg * 8];
            bl[ni] = *(const bf16x8*)&BsL[col * 32 + kg * 8];
        }
        #pragma unroll
        for (int mi = 0; mi < 4; ++mi)
            #pragma unroll
            for (int ni = 0; ni < 4; ++ni) {
                MFMA3(ah[mi], al[mi], bh[ni], bl[ni], acc[mi][ni]);
            }
        __syncthreads();
    }

    int i_base = ib * 128 + wq_i * 64;
    int j_base = jb * 128 + wq_j * 64;
    #pragma unroll
    for (int ni = 0; ni < 4; ++ni) {
        int j = j_base + ni * 16 + fr;
        float bv = -INFINITY; int bi = 0x7fffffff;
        #pragma unroll
        for (int mi = 0; mi < 4; ++mi)
            #pragma unroll
            for (int r = 0; r < 4; ++r) {
                int i = i_base + mi * 16 + kg * 4 + r;
                float v = acc[mi][ni][r];
                if (i < j && v > bv) { bv = v; bi = i; }
            }
        #pragma unroll
        for (int d = 16; d < 64; d <<= 1) {
            float ov = __shfl_xor(bv, d, 64);
            int   oi = __shfl_xor(bi, d, 64);
            if (ov > bv || (ov == bv && oi < bi)) { bv = ov; bi = oi; }
        }
        if (lane < 16) {
            sredv[wq_i * 128 + wq_j * 64 + ni * 16 + lane] = bv;
            sredi[wq_i * 128 + wq_j * 64 + ni * 16 + lane] = bi;
        }
    }
    __syncthreads();
    if (t < 128) {
        float v0 = sredv[t]; int i0 = sredi[t];
        float v1 = sredv[128 + t]; int i1 = sredi[128 + t];
        if (v1 > v0) { v0 = v1; i0 = i1; }
        pmax[(((size_t)n * 32 + ib) << 12) + jb * 128 + t] = v0;
        parg[(((size_t)n * 32 + ib) << 12) + jb * 128 + t] = i0;
    }
}

// ---------------- MFMA split-bf16 masked conv (implicit GEMM) ----------------
__global__ __launch_bounds__(128) void mfma_conv(
    const ushort_t* __restrict__ WH, const ushort_t* __restrict__ WL,
    const float* __restrict__ bias,
    const ushort_t* __restrict__ YH, const ushort_t* __restrict__ YL,
    uint64_t tapenc, int Ktot,
    ushort_t* __restrict__ outH, ushort_t* __restrict__ outL)
{
    __shared__ __align__(16) ushort_t AsH[64 * 32], AsL[64 * 32];
    __shared__ __align__(16) ushort_t BsH[128 * 32], BsL[128 * 32];
    int t = threadIdx.x, w = t >> 6, lane = t & 63;
    int p0 = blockIdx.x << 7, o0 = blockIdx.y << 6, n = blockIdx.z;
    int colq = lane >> 2, ks = lane & 3;
    int fr = lane & 15, kg = lane >> 4;
    int h0 = p0 >> 6;
    const ushort_t* yh = YH + (size_t)n * 4624 * 128;
    const ushort_t* yl = YL + (size_t)n * 4624 * 128;

    const ushort_t* aSrcH0 = WH + (size_t)(o0 + (2 * w + 0) * 16 + colq) * Ktot + ks * 8;
    const ushort_t* aSrcH1 = WH + (size_t)(o0 + (2 * w + 1) * 16 + colq) * Ktot + ks * 8;
    const ushort_t* aSrcL0 = WL + (size_t)(o0 + (2 * w + 0) * 16 + colq) * Ktot + ks * 8;
    const ushort_t* aSrcL1 = WL + (size_t)(o0 + (2 * w + 1) * 16 + colq) * Ktot + ks * 8;

    f32x4 acc[4][4];
    #pragma unroll
    for (int mi = 0; mi < 4; ++mi)
        #pragma unroll
        for (int ni = 0; ni < 4; ++ni) acc[mi][ni] = (f32x4){0.f, 0.f, 0.f, 0.f};

    for (int k0 = 0; k0 < Ktot; k0 += 32) {
        int tp = k0 >> 7, coff = (k0 & 127) + ks * 8;
        int f = (int)((tapenc >> (5 * tp)) & 31);
        int dh = (f & 3) - 2, dw = ((f >> 2) & 7) - 2;
        gll16(aSrcH0 + k0, &AsH[(2 * w + 0) * 512]);
        gll16(aSrcH1 + k0, &AsH[(2 * w + 1) * 512]);
        gll16(aSrcL0 + k0, &AsL[(2 * w + 0) * 512]);
        gll16(aSrcL1 + k0, &AsL[(2 * w + 1) * 512]);
        #pragma unroll
        for (int cb = 0; cb < 4; ++cb) {
            int c = w * 64 + cb * 16 + colq;
            int prow = (h0 + (c >> 6) + 1 + dh) * 68 + (c & 63) + 1 + dw;
            gll16(yh + (size_t)prow * 128 + coff, &BsH[(w * 4 + cb) * 512]);
            gll16(yl + (size_t)prow * 128 + coff, &BsL[(w * 4 + cb) * 512]);
        }
#ifdef HAVE_GLL
        asm volatile("s_waitcnt vmcnt(0)" ::: "memory");
#endif
        __syncthreads();
        bf16x8 ah[4], al[4], bh[4], bl[4];
        #pragma unroll
        for (int mi = 0; mi < 4; ++mi) {
            int col = mi * 16 + fr;
            ah[mi] = *(const bf16x8*)&AsH[col * 32 + kg * 8];
            al[mi] = *(const bf16x8*)&AsL[col * 32 + kg * 8];
        }
        #pragma unroll
        for (int ni = 0; ni < 4; ++ni) {
            int col = w * 64 + ni * 16 + fr;
            bh[ni] = *(const bf16x8*)&BsH[col * 32 + kg * 8];
            bl[ni] = *(const bf16x8*)&BsL[col * 32 + kg * 8];
        }
        #pragma unroll
        for (int mi = 0; mi < 4; ++mi)
            #pragma unroll
            for (int ni = 0; ni < 4; ++ni) {
                MFMA3(ah[mi], al[mi], bh[ni], bl[ni], acc[mi][ni]);
            }
        __syncthreads();
    }

    #pragma unroll
    for (int mi = 0; mi < 4; ++mi) {
        int og = o0 + mi * 16 + kg * 4;
        f32x4 bv = (f32x4){0.f, 0.f, 0.f, 0.f};
        if (bias) bv = *(const f32x4*)&bias[og];
        #pragma unroll
        for (int ni = 0; ni < 4; ++ni) {
            int p = p0 + w * 64 + ni * 16 + fr;
            f32x4 v = acc[mi][ni] + bv;
            ushort_t h0s = f2bf_rne(v[0]), h1s = f2bf_rne(v[1]), h2s = f2bf_rne(v[2]), h3s = f2bf_rne(v[3]);
            size_t db = (((size_t)n << 12) + p) * 256 + og;
            *(uint2*)&outH[db] = make_uint2(h0s | ((uint32_t)h1s << 16), h2s | ((uint32_t)h3s << 16));
            ushort_t l0s = f2bf_rne(v[0] - bf2f(h0s)), l1s = f2bf_rne(v[1] - bf2f(h1s));
            ushort_t l2s = f2bf_rne(v[2] - bf2f(h2s)), l3s = f2bf_rne(v[3] - bf2f(h3s));
            *(uint2*)&outL[db] = make_uint2(l0s | ((uint32_t)l1s << 16), l2s | ((uint32_t)l3s << 16));
        }
    }
}

// ---------------- MFMA split-bf16 dense 1x1 GEMM (rf projections: mode 2) ----------------
__global__ __launch_bounds__(128) void mfma_dense(
    const ushort_t* __restrict__ WH, const ushort_t* __restrict__ WL,
    const ushort_t* __restrict__ B0H, const ushort_t* __restrict__ B0L, int str0,
    int Ktot, float* __restrict__ outF)
{
    __shared__ __align__(16) ushort_t AsH[64 * 32], AsL[64 * 32];
    __shared__ __align__(16) ushort_t BsH[128 * 32], BsL[128 * 32];
    int t = threadIdx.x, w = t >> 6, lane = t & 63;
    int p0 = blockIdx.x << 7, o0 = blockIdx.y << 6, n = blockIdx.z;
    int colq = lane >> 2, ks = lane & 3;
    int fr = lane & 15, kg = lane >> 4;

    const ushort_t* aSrcH0 = WH + (size_t)(o0 + (2 * w + 0) * 16 + colq) * Ktot + ks * 8;
    const ushort_t* aSrcH1 = WH + (size_t)(o0 + (2 * w + 1) * 16 + colq) * Ktot + ks * 8;
    const ushort_t* aSrcL0 = WL + (size_t)(o0 + (2 * w + 0) * 16 + colq) * Ktot + ks * 8;
    const ushort_t* aSrcL1 = WL + (size_t)(o0 + (2 * w + 1) * 16 + colq) * Ktot + ks * 8;
    size_t brow[4];
    #pragma unroll
    for (int cb = 0; cb < 4; ++cb)
        brow[cb] = ((size_t)n << 12) + p0 + w * 64 + cb * 16 + colq;

    f32x4 acc[4][4];
    #pragma unroll
    for (int mi = 0; mi < 4; ++mi)
        #pragma unroll
        for (int ni = 0; ni < 4; ++ni) acc[mi][ni] = (f32x4){0.f, 0.f, 0.f, 0.f};

    for (int k0 = 0; k0 < Ktot; k0 += 32) {
        gll16(aSrcH0 + k0, &AsH[(2 * w + 0) * 512]);
        gll16(aSrcH1 + k0, &AsH[(2 * w + 1) * 512]);
        gll16(aSrcL0 + k0, &AsL[(2 * w + 0) * 512]);
        gll16(aSrcL1 + k0, &AsL[(2 * w + 1) * 512]);
        int kk = k0 + ks * 8;
        #pragma unroll
        for (int cb = 0; cb < 4; ++cb) {
            gll16(B0H + brow[cb] * str0 + kk, &BsH[(w * 4 + cb) * 512]);
            gll16(B0L + brow[cb] * str0 + kk, &BsL[(w * 4 + cb) * 512]);
        }
#ifdef HAVE_GLL
        asm volatile("s_waitcnt vmcnt(0)" ::: "memory");
#endif
        __syncthreads();
        bf16x8 ah[4], al[4], bh[4], bl[4];
        #pragma unroll
        for (int mi = 0; mi < 4; ++mi) {
            int col = mi * 16 + fr;
            ah[mi] = *(const bf16x8*)&AsH[col * 32 + kg * 8];
            al[mi] = *(const bf16x8*)&AsL[col * 32 + kg * 8];
        }
        #pragma unroll
        for (int ni = 0; ni < 4; ++ni) {
            int col = w * 64 + ni * 16 + fr;
            bh[ni] = *(const bf16x8*)&BsH[col * 32 + kg * 8];
            bl[ni] = *(const bf16x8*)&BsL[col * 32 + kg * 8];
        }
        #pragma unroll
        for (int mi = 0; mi < 4; ++mi)
            #pragma unroll
            for (int ni = 0; ni < 4; ++ni) {
                MFMA3(ah[mi], al[mi], bh[ni], bl[ni], acc[mi][ni]);
            }
        __syncthreads();
    }

    #pragma unroll
    for (int mi = 0; mi < 4; ++mi) {
        int og = o0 + mi * 16 + kg * 4;
        #pragma unroll
        for (int ni = 0; ni < 4; ++ni) {
            int p = p0 + w * 64 + ni * 16 + fr;
            *(f32x4*)&outF[(((size_t)n << 12) + p) * 128 + og] = acc[mi][ni];
        }
    }
}

// ---------------- fused 3-layer MLP ----------------
// 256 thr = 4 waves; P-tile 128. h1/h2 live in LDS ([p][o], XOR-swizzled).
// Weights fragment-loaded from global (L2-resident). 3 barriers total.
struct MlpCfg {
    const ushort_t *waH, *waL; const float* ba; int Ka;
    const ushort_t *wbH, *wbL; const float* bb;
    const ushort_t *wcH, *wcL; const float* bc;
    const ushort_t *x0H, *x0L; int k0len, str0;
    const ushort_t *x1H, *x1L; int str1;
    const float* gatherP; int addLsu;
    float* outBase;
};

__global__ __launch_bounds__(256) void mlp_fused(MlpCfg c0, MlpCfg c1,
    const int* __restrict__ argi, const float* __restrict__ lsu)
{
    __shared__ __align__(16) ushort_t hbH[16384];
    __shared__ __align__(16) ushort_t hbL[16384];
    const MlpCfg c = blockIdx.y ? c1 : c0;
    int t = threadIdx.x, lane = t & 63, w = t >> 6;
    int fr = lane & 15, kg = lane >> 4;
    int p0 = blockIdx.x << 7, n = blockIdx.z;

    // ---- L1: O=128, K=Ka (x from global), leaky, optional gather; -> hbuf
    {
        int o_t = w >> 1, p_h = w & 1;
        f32x4 acc[4][4];
        #pragma unroll
        for (int mi = 0; mi < 4; ++mi)
            #pragma unroll
            for (int ni = 0; ni < 4; ++ni) acc[mi][ni] = (f32x4){0.f, 0.f, 0.f, 0.f};
        for (int k0 = 0; k0 < c.Ka; k0 += 32) {
            const ushort_t *xh, *xl; int kk, str;
            if (k0 < c.k0len) { xh = c.x0H; xl = c.x0L; kk = k0; str = c.str0; }
            else              { xh = c.x1H; xl = c.x1L; kk = k0 - c.k0len; str = c.str1; }
            kk += kg * 8;
            bf16x8 ah[4], al[4], bh[4], bl[4];
            #pragma unroll
            for (int ni = 0; ni < 4; ++ni) {
                size_t row = ((size_t)n << 12) + p0 + p_h * 64 + ni * 16 + fr;
                bh[ni] = *(const bf16x8*)&xh[row * str + kk];
                bl[ni] = *(const bf16x8*)&xl[row * str + kk];
            }
            #pragma unroll
            for (int mi = 0; mi < 4; ++mi) {
                size_t orow = (size_t)(o_t * 64 + mi * 16 + fr) * c.Ka + k0 + kg * 8;
                ah[mi] = *(const bf16x8*)&c.waH[orow];
                al[mi] = *(const bf16x8*)&c.waL[orow];
            }
            #pragma unroll
            for (int mi = 0; mi < 4; ++mi)
                #pragma unroll
                for (int ni = 0; ni < 4; ++ni) {
                    MFMA3(ah[mi], al[mi], bh[ni], bl[ni], acc[mi][ni]);
                }
        }
        #pragma unroll
        for (int mi = 0; mi < 4; ++mi) {
            int og = o_t * 64 + mi * 16 + kg * 4;
            f32x4 bv = *(const f32x4*)&c.ba[og];
            #pragma unroll
            for (int ni = 0; ni < 4; ++ni) {
                int p_loc = p_h * 64 + ni * 16 + fr;
                int p = p0 + p_loc;
                f32x4 v = acc[mi][ni] + bv;
                if (c.gatherP) {
                    int aj = argi[(n << 12) + p];
                    if (aj >= 0) v += *(const f32x4*)&c.gatherP[(((size_t)n << 12) + aj) * 128 + og];
                }
                #pragma unroll
                for (int r = 0; r < 4; ++r) v[r] = v[r] > 0.f ? v[r] : 0.2f * v[r];
                int osw = og ^ ((p_loc & 7) << 3);
                ushort_t h0s = f2bf_rne(v[0]), h1s = f2bf_rne(v[1]), h2s = f2bf_rne(v[2]), h3s = f2bf_rne(v[3]);
                *(uint2*)&hbH[p_loc * 128 + osw] = make_uint2(h0s | ((uint32_t)h1s << 16), h2s | ((uint32_t)h3s << 16));
                ushort_t l0s = f2bf_rne(v[0] - bf2f(h0s)), l1s = f2bf_rne(v[1] - bf2f(h1s));
                ushort_t l2s = f2bf_rne(v[2] - bf2f(h2s)), l3s = f2bf_rne(v[3] - bf2f(h3s));
                *(uint2*)&hbL[p_loc * 128 + osw] = make_uint2(l0s | ((uint32_t)l1s << 16), l2s | ((uint32_t)l3s << 16));
            }
        }
    }
    __syncthreads();
    // ---- L2: O=128, K=128 (B from hbuf), leaky; -> hbuf (after barrier)
    {
        int o_t = w >> 1, p_h = w & 1;
        f32x4 acc[4][4];
        #pragma unroll
        for (int mi = 0; mi < 4; ++mi)
            #pragma unroll
            for (int ni = 0; ni < 4; ++ni) acc[mi][ni] = (f32x4){0.f, 0.f, 0.f, 0.f};
        for (int k0 = 0; k0 < 128; k0 += 32) {
            bf16x8 ah[4], al[4], bh[4], bl[4];
            #pragma unroll
            for (int ni = 0; ni < 4; ++ni) {
                int p_loc = p_h * 64 + ni * 16 + fr;
                int koff = (k0 + kg * 8) ^ ((p_loc & 7) << 3);
                bh[ni] = *(const bf16x8*)&hbH[p_loc * 128 + koff];
                bl[ni] = *(const bf16x8*)&hbL[p_loc * 128 + koff];
            }
            #pragma unroll
            for (int mi = 0; mi < 4; ++mi) {
                size_t orow = (size_t)(o_t * 64 + mi * 16 + fr) * 128 + k0 + kg * 8;
                ah[mi] = *(const bf16x8*)&c.wbH[orow];
                al[mi] = *(const bf16x8*)&c.wbL[orow];
            }
            #pragma unroll
            for (int mi = 0; mi < 4; ++mi)
                #pragma unroll
                for (int ni = 0; ni < 4; ++ni) {
                    MFMA3(ah[mi], al[mi], bh[ni], bl[ni], acc[mi][ni]);
                }
        }
        __syncthreads(); // all h1 reads complete before overwrite
        #pragma unroll
        for (int mi = 0; mi < 4; ++mi) {
            int og = o_t * 64 + mi * 16 + kg * 4;
            f32x4 bv = *(const f32x4*)&c.bb[og];
            #pragma unroll
            for (int ni = 0; ni < 4; ++ni) {
                int p_loc = p_h * 64 + ni * 16 + fr;
                f32x4 v = acc[mi][ni] + bv;
                #pragma unroll
                for (int r = 0; r < 4; ++r) v[r] = v[r] > 0.f ? v[r] : 0.2f * v[r];
                int osw = og ^ ((p_loc & 7) << 3);
                ushort_t h0s = f2bf_rne(v[0]), h1s = f2bf_rne(v[1]), h2s = f2bf_rne(v[2]), h3s = f2bf_rne(v[3]);
                *(uint2*)&hbH[p_loc * 128 + osw] = make_uint2(h0s | ((uint32_t)h1s << 16), h2s | ((uint32_t)h3s << 16));
                ushort_t l0s = f2bf_rne(v[0] - bf2f(h0s)), l1s = f2bf_rne(v[1] - bf2f(h1s));
                ushort_t l2s = f2bf_rne(v[2] - bf2f(h2s)), l3s = f2bf_rne(v[3] - bf2f(h3s));
                *(uint2*)&hbL[p_loc * 128 + osw] = make_uint2(l0s | ((uint32_t)l1s << 16), l2s | ((uint32_t)l3s << 16));
            }
        }
    }
    __syncthreads();
    // ---- L3: O=384, K=128; 12 units of 64x64, 3 per wave; -> global f32
    for (int it = 0; it < 3; ++it) {
        int u = w + 4 * it;
        int o_t = u >> 1, p_h = u & 1;
        f32x4 acc[4][4];
        #pragma unroll
        for (int mi = 0; mi < 4; ++mi)
            #pragma unroll
            for (int ni = 0; ni < 4; ++ni) acc[mi][ni] = (f32x4){0.f, 0.f, 0.f, 0.f};
        for (int k0 = 0; k0 < 128; k0 += 32) {
            bf16x8 ah[4], al[4], bh[4], bl[4];
            #pragma unroll
            for (int ni = 0; ni < 4; ++ni) {
                int p_loc = p_h * 64 + ni * 16 + fr;
                int koff = (k0 + kg * 8) ^ ((p_loc & 7) << 3);
                bh[ni] = *(const bf16x8*)&hbH[p_loc * 128 + koff];
                bl[ni] = *(const bf16x8*)&hbL[p_loc * 128 + koff];
            }
            #pragma unroll
            for (int mi = 0; mi < 4; ++mi) {
                size_t orow = (size_t)(o_t * 64 + mi * 16 + fr) * 128 + k0 + kg * 8;
                ah[mi] = *(const bf16x8*)&c.wcH[orow];
                al[mi] = *(const bf16x8*)&c.wcL[orow];
            }
            #pragma unroll
            for (int mi = 0; mi < 4; ++mi)
                #pragma unroll
                for (int ni = 0; ni < 4; ++ni) {
                    MFMA3(ah[mi], al[mi], bh[ni], bl[ni], acc[mi][ni]);
                }
        }
        #pragma unroll
        for (int mi = 0; mi < 4; ++mi) {
            int og = o_t * 64 + mi * 16 + kg * 4;
            f32x4 bv = *(const f32x4*)&c.bc[og];
            #pragma unroll
            for (int ni = 0; ni < 4; ++ni) {
                int p = p0 + p_h * 64 + ni * 16 + fr;
                f32x4 v = acc[mi][ni] + bv;
                if (c.addLsu && og < 128) {
                    float lv = lsu[(n << 12) + p];
                    v[0] += lv; v[1] += lv; v[2] += lv; v[3] += lv;
                }
                float* dst = c.outBase + (((size_t)(n * 384 + og)) << 12) + p;
                dst[0] = v[0]; dst[4096] = v[1]; dst[8192] = v[2]; dst[12288] = v[3];
            }
        }
    }
}

// ---------------- y_prob from para1 ----------------
__global__ __launch_bounds__(256) void yprob_kernel(
    const float* __restrict__ out, const float* __restrict__ y, float* __restrict__ ws)
{
    int idx = blockIdx.x * 256 + threadIdx.x;
    int n = idx >> 12, p = idx & 4095;
    const float* pw = out + OUT_P1 + (size_t)n * 384 * 4096 + p;
    const float* pm = pw + (size_t)128 * 4096;
    const float* psv = pm + (size_t)128 * 4096;
    const float* yy = y + (size_t)n * 128 * 4096 + p;
    float accs = 0.f;
    for (int c = 0; c < 128; ++c) {
        float w  = pw[(size_t)c * 4096];
        float mu = pm[(size_t)c * 4096];
        float ls = psv[(size_t)c * 4096];
        ls = fminf(fmaxf(ls, -7.f), 7.f);
        float tt = (yy[(size_t)c * 4096] - mu) * expf(-ls);
        float lsig = (w >= 0.f) ? -log1pf(expf(-w)) : (w - log1pf(expf(w)));
        float nll = 0.5f * tt * tt + ls + 0.9189385f - lsig;
        accs += expf(-nll);
    }
    ws[WS_YPROB + idx] = accs * (1.0f / 128.0f);
}

// ---------------- merge tile partials, emit S/U/R_arg ----------------
__global__ __launch_bounds__(256) void finalize_kernel(float* __restrict__ ws, float* __restrict__ out)
{
    int idx = blockIdx.x * 256 + threadIdx.x;
    int n = idx >> 12, j = idx & 4095;
    float s, u; int a;
    if (j == 0) { s = 1e-8f; u = 1e-8f; a = -1; }
    else {
        float bv = -INFINITY; int bi = 0x7fffffff;
        const int* pai = (const int*)ws;
        int jbt = j >> 7;
        for (int ib = 0; ib <= jbt; ++ib) {
            float v = ws[WS_PMAX + (((size_t)n * 32 + ib) << 12) + j];
            int ii = pai[WS_PARG + (((size_t)n * 32 + ib) << 12) + j];
            if (v > bv || (v == bv && ii < bi)) { bv = v; bi = ii; }
        }
        s = fminf(fmaxf(bv, 1e-8f), 1.0f);
        if (bi < 0 || bi > 4095) bi = 0;
        float yp = ws[WS_YPROB + ((size_t)n << 12) + bi];
        u = fminf(fmaxf(yp, 1e-8f), 1.0f);
        a = bi;
    }
    out[OUT_S + idx] = s;
    out[OUT_U + idx] = u;
    out[OUT_RA + idx] = (float)a;
    ((int*)ws)[WS_ARGI + idx] = a;
    ws[WS_LSU + idx] = logf(s + 1e-8f) + logf(u + 1e-8f);
}

// ---------------- launch ----------------
extern "C" void kernel_launch(void* const* d_in, const int* in_sizes, int n_in,
                              void* d_out, int out_size, void* d_ws, size_t ws_size,
                              hipStream_t stream)
{
    const float* y   = (const float*)d_in[0];
    const float* z   = (const float*)d_in[1];
    const float* w5  = (const float*)d_in[2];
    const float* b5  = (const float*)d_in[3];
    const float* w1a = (const float*)d_in[4];
    const float* b1a = (const float*)d_in[5];
    const float* w1b = (const float*)d_in[6];
    const float* b1b = (const float*)d_in[7];
    const float* w1c = (const float*)d_in[8];
    const float* b1c = (const float*)d_in[9];
    const float* wrf = (const float*)d_in[10];
    const float* w2a = (const float*)d_in[11];
    const float* b2a = (const float*)d_in[12];
    const float* w2b = (const float*)d_in[13];
    const float* b2b = (const float*)d_in[14];
    const float* w2c = (const float*)d_in[15];
    const float* b2c = (const float*)d_in[16];
    const float* w3a = (const float*)d_in[17];
    const float* b3a = (const float*)d_in[18];
    const float* w3b = (const float*)d_in[19];
    const float* b3b = (const float*)d_in[20];
    const float* w3c = (const float*)d_in[21];
    const float* b3c = (const float*)d_in[22];
    float* ws  = (float*)d_ws;
    float* out = (float*)d_out;
    const int* argi = (const int*)(ws) + WS_ARGI;

    ushort_t* wph = (ushort_t*)(ws + WS_WPK);
    ushort_t* wpl = wph + 933888;
    ushort_t* locH = (ushort_t*)(ws + WS_LOCH);
    ushort_t* locL = (ushort_t*)(ws + WS_LOCL);
    ushort_t* ftH  = (ushort_t*)(ws + WS_FTH);
    ushort_t* ftL  = (ushort_t*)(ws + WS_FTL);
    float* p2t = ws + WS_P2T;
    float* p3t = ws + WS_P3T;
    ushort_t* ztpH = (ushort_t*)(ws + WS_ZTPH);
    ushort_t* ztpL = (ushort_t*)(ws + WS_ZTPL);
    ushort_t* ytpH = (ushort_t*)(out + OS_YTPH);
    ushort_t* ytpL = (ushort_t*)(out + OS_YTPL);

    repack_split<<<3648, 256, 0, stream>>>(w5, wrf, w1a, w1b, w1c, w2a, w2b, w2c, w3a, w3b, w3c, wph, wpl);
    padclear<<<2312, 256, 0, stream>>>(out + OS_YTPH);
    transsplit<<<dim3(4, 64, NB), 256, 0, stream>>>(y, ytpH, ytpL, 1);
    transsplit<<<dim3(4, 64, NB), 256, 0, stream>>>(z, ztpH, ztpL, 0);
    sumsq_kernel<<<64, 256, 0, stream>>>(y, ws);
    rnorm_kernel<<<64, 256, 0, stream>>>(ws);
    vbuild_kernel<<<32768, 256, 0, stream>>>(ytpH, ytpL, ws);
    gram_mfma<<<dim3(528, NB), 256, 0, stream>>>((const ushort_t*)(ws + WS_VH), (const ushort_t*)(ws + WS_VL),
                                                 ws + WS_PMAX, (int*)(ws + WS_PARG));

    // conv5 -> localT (overwrites V; gram done, stream-ordered); conv3 -> FT
    mfma_conv<<<dim3(32, 4, NB), 128, 0, stream>>>(wph + WP_W5, wpl + WP_W5, b5, ytpH, ytpL, ENC5, 1536, locH, locL);
    mfma_conv<<<dim3(32, 4, NB), 128, 0, stream>>>(wph + WP_WR, wpl + WP_WR, nullptr, ytpH, ytpL, ENC3, 640, ftH, ftL);
    // rf projections -> P2T/P3T (f32 transposed [n][4096][128])
    mfma_dense<<<dim3(32, 2, NB), 128, 0, stream>>>(wph + WP_W2AR, wpl + WP_W2AR, ftH, ftL, 256, 256, p2t);
    mfma_dense<<<dim3(32, 2, NB), 128, 0, stream>>>(wph + WP_W3AR, wpl + WP_W3AR, ftH, ftL, 256, 256, p3t);

    // mlp1 fused -> para1
    MlpCfg m1;
    m1.waH = wph + WP_W1A; m1.waL = wpl + WP_W1A; m1.ba = b1a; m1.Ka = 256;
    m1.wbH = wph + WP_W1B; m1.wbL = wpl + WP_W1B; m1.bb = b1b;
    m1.wcH = wph + WP_W1C; m1.wcL = wpl + WP_W1C; m1.bc = b1c;
    m1.x0H = locH; m1.x0L = locL; m1.k0len = 256; m1.str0 = 256;
    m1.x1H = locH; m1.x1L = locL; m1.str1 = 256;
    m1.gatherP = nullptr; m1.addLsu = 0; m1.outBase = out + OUT_P1;
    mlp_fused<<<dim3(32, 1, NB), 256, 0, stream>>>(m1, m1, argi, ws + WS_LSU);

    yprob_kernel<<<64, 256, 0, stream>>>(out, y, ws);
    finalize_kernel<<<64, 256, 0, stream>>>(ws, out);

    // mlp2 + mlp3 fused (single launch, blockIdx.y selects)
    MlpCfg m2;
    m2.waH = wph + WP_W2AL; m2.waL = wpl + WP_W2AL; m2.ba = b2a; m2.Ka = 256;
    m2.wbH = wph + WP_W2B; m2.wbL = wpl + WP_W2B; m2.bb = b2b;
    m2.wcH = wph + WP_W2C; m2.wcL = wpl + WP_W2C; m2.bc = b2c;
    m2.x0H = locH; m2.x0L = locL; m2.k0len = 256; m2.str0 = 256;
    m2.x1H = locH; m2.x1L = locL; m2.str1 = 256;
    m2.gatherP = p2t; m2.addLsu = 1; m2.outBase = out + OUT_P2;
    MlpCfg m3;
    m3.waH = wph + WP_W3ALZ; m3.waL = wpl + WP_W3ALZ; m3.ba = b3a; m3.Ka = 384;
    m3.wbH = wph + WP_W3B; m3.wbL = wpl + WP_W3B; m3.bb = b3b;
    m3.wcH = wph + WP_W3C; m3.wcL = wpl + WP_W3C; m3.bc = b3c;
    m3.x0H = locH; m3.x0L = locL; m3.k0len = 256; m3.str0 = 256;
    m3.x1H = ztpH; m3.x1L = ztpL; m3.str1 = 128;
    m3.gatherP = p3t; m3.addLsu = 0; m3.outBase = out + OUT_P3;
    mlp_fused<<<dim3(32, 2, NB), 256, 0, stream>>>(m2, m3, argi, ws + WS_LSU);

    (void)in_sizes; (void)n_in; (void)out_size; (void)ws_size;
}

// Round 5
// 517.839 us; speedup vs baseline: 4.6685x; 1.2038x over previous
//
#include <hip/hip_runtime.h>
#include <cstdint>
#include <cstddef>

typedef unsigned short ushort_t;
typedef __attribute__((ext_vector_type(8))) short bf16x8;
typedef __attribute__((ext_vector_type(4))) float f32x4;

#if defined(__has_builtin)
#if __has_builtin(__builtin_amdgcn_global_load_lds)
#define HAVE_GLL 1
#endif
#endif

// ---------------- constants ----------------
constexpr int NB = 4;
// d_out offsets (floats)
constexpr size_t OUT_P1 = 0;
constexpr size_t OUT_P2 = 6291456;
constexpr size_t OUT_P3 = 12582912;
constexpr size_t OUT_S  = 18874368;
constexpr size_t OUT_U  = 18890752;
constexpr size_t OUT_RA = 18907136;

// ---------------- workspace layout (float elements) ----------------
constexpr size_t WS_SS    = 0;
constexpr size_t WS_RNORM = 16384;
constexpr size_t WS_YPROB = 32768;
constexpr size_t WS_ARGI  = 49152;
constexpr size_t WS_LSU   = 65536;
constexpr size_t WS_PMAX  = 81920;    // 524288 (n,32,4096)
constexpr size_t WS_PARG  = 606208;   // 524288 (int)
constexpr size_t WS_WPK   = 1130496;  // 2x 933888 ushort (h then l)
constexpr size_t WS_BIG   = 2064384;
constexpr size_t WS_VH    = WS_BIG;
constexpr size_t WS_VL    = WS_BIG + 4194304;
// aliased after gram: localT h/l + FT h/l
constexpr size_t WS_LOCH  = WS_BIG;
constexpr size_t WS_LOCL  = WS_BIG + 2097152;
constexpr size_t WS_FTH   = WS_BIG + 4194304;
constexpr size_t WS_FTL   = WS_BIG + 6291456;
constexpr size_t WS_P2T   = 10452992; // fp32 [n][4096][128]
constexpr size_t WS_P3T   = 12550144;
constexpr size_t WS_ZTPH  = 14647296; // 2097152 ushorts = 1048576 floats
constexpr size_t WS_ZTPL  = 15695872; // end 16744448

// d_out scratch (OUT_P3 region; read only before mlp23 writes OUT_P3)
constexpr size_t OS_YTPH  = 12582912; // 2367488 ushorts
constexpr size_t OS_YTPL  = 13766656; // end 14950400 < OUT_S

// weight pack sub-offsets (ushort units)
constexpr size_t WP_W5   = 0;
constexpr size_t WP_WR   = 393216;
constexpr size_t WP_W1A  = 557056;
constexpr size_t WP_W1B  = 589824;
constexpr size_t WP_W1C  = 606208;
constexpr size_t WP_W2AL = 655360;
constexpr size_t WP_W2AR = 688128;
constexpr size_t WP_W2B  = 720896;
constexpr size_t WP_W2C  = 737280;
constexpr size_t WP_W3ALZ= 786432;
constexpr size_t WP_W3AR = 835584;
constexpr size_t WP_W3B  = 868352;
constexpr size_t WP_W3C  = 884736;

constexpr uint64_t TENC(int i, int dh, int dw) {
    return ((uint64_t)((dh + 2) | ((dw + 2) << 2))) << (5 * i);
}
constexpr uint64_t ENC5 = TENC(0,-2,-2)|TENC(1,-2,-1)|TENC(2,-2,0)|TENC(3,-2,1)|TENC(4,-2,2)
                        | TENC(5,-1,-2)|TENC(6,-1,-1)|TENC(7,-1,0)|TENC(8,-1,1)|TENC(9,-1,2)
                        | TENC(10,0,-2)|TENC(11,0,-1);
constexpr uint64_t ENC3 = TENC(0,-1,-1)|TENC(1,-1,0)|TENC(2,-1,1)|TENC(3,0,-1)|TENC(4,0,0);

static __device__ inline ushort_t f2bf_rne(float f) {
    uint32_t u = __float_as_uint(f);
    uint32_t r = (u + 0x7fffu + ((u >> 16) & 1u)) >> 16;
    return (ushort_t)r;
}
static __device__ inline float bf2f(ushort_t h) {
    return __uint_as_float(((uint32_t)h) << 16);
}

static __device__ inline void gll16(const ushort_t* g, ushort_t* l) {
#ifdef HAVE_GLL
    __builtin_amdgcn_global_load_lds((const __attribute__((address_space(1))) void*)g,
                                     (__attribute__((address_space(3))) void*)l, 16, 0, 0);
#else
    uint4 v = *(const uint4*)g;
    *(uint4*)((char*)l + (threadIdx.x & 63) * 16) = v;
#endif
}

#define MFMA3(AH, AL, BH, BL, ACC) \
    ACC = __builtin_amdgcn_mfma_f32_16x16x32_bf16(AH, BH, ACC, 0, 0, 0); \
    ACC = __builtin_amdgcn_mfma_f32_16x16x32_bf16(AH, BL, ACC, 0, 0, 0); \
    ACC = __builtin_amdgcn_mfma_f32_16x16x32_bf16(AL, BH, ACC, 0, 0, 0);

// ---------------- fused prep: repack + pad-ring clear + 2 transposes ----------------
// grid: [0,3648) repack | [3648,3912) ring clear | [3912,4936) y-trans | [4936,5960) z-trans
__global__ __launch_bounds__(256) void prep_fused(
    const float* __restrict__ w5, const float* __restrict__ wr,
    const float* __restrict__ w1a, const float* __restrict__ w1b, const float* __restrict__ w1c,
    const float* __restrict__ w2a, const float* __restrict__ w2b, const float* __restrict__ w2c,
    const float* __restrict__ w3a, const float* __restrict__ w3b, const float* __restrict__ w3c,
    const float* __restrict__ y, const float* __restrict__ z,
    ushort_t* __restrict__ WH, ushort_t* __restrict__ WL,
    ushort_t* __restrict__ ytpH, ushort_t* __restrict__ ytpL,
    ushort_t* __restrict__ ztpH, ushort_t* __restrict__ ztpL)
{
    __shared__ float tile[128][17];
    int b = blockIdx.x, t = threadIdx.x;
    if (b < 3648) {
        int idx = b * 256 + t;
        if (idx >= 933888) return;
        float v; int i = idx;
        if (i < 393216) {
            int o = i / 1536, k = i % 1536; int tp = k >> 7, c = k & 127;
            int f = (int)((ENC5 >> (5 * tp)) & 31); int dh = (f & 3) - 2, dw = ((f >> 2) & 7) - 2;
            v = w5[((size_t)(o * 128 + c)) * 25 + (dh + 2) * 5 + (dw + 2)];
        } else if ((i -= 393216) < 163840) {
            int o = i / 640, k = i % 640; int tp = k >> 7, c = k & 127;
            int f = (int)((ENC3 >> (5 * tp)) & 31); int dh = (f & 3) - 2, dw = ((f >> 2) & 7) - 2;
            v = wr[((size_t)(o * 128 + c)) * 9 + (dh + 1) * 3 + (dw + 1)];
        }
        else if ((i -= 163840) < 32768) v = w1a[i];
        else if ((i -= 32768) < 16384) v = w1b[i];
        else if ((i -= 16384) < 49152) v = w1c[i];
        else if ((i -= 49152) < 32768) { int o = i >> 8, k = i & 255; v = w2a[o * 512 + k]; }
        else if ((i -= 32768) < 32768) { int o = i >> 8, k = i & 255; v = w2a[o * 512 + 256 + k]; }
        else if ((i -= 32768) < 16384) v = w2b[i];
        else if ((i -= 16384) < 49152) v = w2c[i];
        else if ((i -= 49152) < 49152) { int o = i / 384, k = i % 384; v = (k < 256) ? w3a[o * 640 + k] : w3a[o * 640 + 512 + (k - 256)]; }
        else if ((i -= 49152) < 32768) { int o = i >> 8, k = i & 255; v = w3a[o * 640 + 256 + k]; }
        else if ((i -= 32768) < 16384) v = w3b[i];
        else { i -= 16384; v = w3c[i]; }
        ushort_t h = f2bf_rne(v);
        WH[idx] = h;
        WL[idx] = f2bf_rne(v - bf2f(h));
        return;
    }
    if (b < 3912) {
        // pad-ring clear: image sits at rows/cols 2..65 of 68x68; ring = rest
        int slot = (b - 3648) * 8 + (t >> 5);  // 0..2111
        int n = slot / 528, rp = slot % 528;
        int r, wcol;
        if (rp < 272) { int x = rp / 68; r = x + ((x >> 1) << 6); wcol = rp % 68; }
        else { int q = rp - 272; r = 2 + (q >> 2); int x = q & 3; wcol = x + ((x >> 1) << 6); }
        size_t row = (size_t)n * 4624 + (size_t)r * 68 + wcol;
        int lane = t & 31;
        ushort_t* dst = ((lane >> 4) ? ytpL : ytpH) + row * 128;
        ((uint4*)dst)[lane & 15] = uint4{0u, 0u, 0u, 0u};
        return;
    }
    // transpose + split
    int b2, pad;
    const float* src;
    ushort_t *dh_, *dl_;
    if (b < 4936) { b2 = b - 3912; pad = 1; src = y; dh_ = ytpH; dl_ = ytpL; }
    else          { b2 = b - 4936; pad = 0; src = z; dh_ = ztpH; dl_ = ztpL; }
    int wc = b2 & 3, h = (b2 >> 2) & 63, n = b2 >> 8;
    {
        int tw = t & 15, tc = t >> 4;
        #pragma unroll
        for (int r = 0; r < 8; ++r) {
            int c = tc * 8 + r;
            tile[c][tw] = src[((size_t)(n * 128 + c) << 12) + (h << 6) + wc * 16 + tw];
        }
    }
    __syncthreads();
    {
        int cc = t & 127, ww = t >> 7;
        #pragma unroll
        for (int r = 0; r < 8; ++r) {
            int w = ww * 8 + r;
            float v = tile[cc][w];
            size_t drow = pad ? ((size_t)n * 4624 + (size_t)(h + 2) * 68 + wc * 16 + w + 2)
                              : ((size_t)n * 4096 + (h << 6) + wc * 16 + w);
            ushort_t hh = f2bf_rne(v);
            dh_[drow * 128 + cc] = hh;
            dl_[drow * 128 + cc] = f2bf_rne(v - bf2f(hh));
        }
    }
}

// ---------------- per-pixel sum of squares (coalesced, 4 ch-groups) ----------------
__global__ __launch_bounds__(256) void sumsq_kernel(const float* __restrict__ y, float* __restrict__ ws)
{
    __shared__ float red[4][64];
    int n = blockIdx.y, t = threadIdx.x;
    int pl = t & 63, cg = t >> 6;
    int p = (blockIdx.x << 6) + pl;
    const float* yp = y + ((size_t)(n * 128 + cg * 32) << 12) + p;
    float s = 0.f;
    #pragma unroll 8
    for (int c = 0; c < 32; ++c) { float v = yp[(size_t)c << 12]; s = fmaf(v, v, s); }
    red[cg][pl] = s;
    __syncthreads();
    if (t < 64)
        ws[WS_SS + ((size_t)n << 12) + (blockIdx.x << 6) + t] =
            red[0][t] + red[1][t] + red[2][t] + red[3][t];
}

__global__ __launch_bounds__(256) void rnorm_kernel(float* __restrict__ ws)
{
    int idx = blockIdx.x * 256 + threadIdx.x;
    int n = idx >> 12, p = idx & 4095;
    int h = p >> 6, w = p & 63;
    const float* ss = ws + WS_SS + ((size_t)n << 12);
    float nsq = 0.f;
    if (h > 0 && w > 0)  nsq += ss[p - 65];
    if (h > 0)           nsq += ss[p - 64];
    if (h > 0 && w < 63) nsq += ss[p - 63];
    if (w > 0)           nsq += ss[p - 1];
    ws[WS_RNORM + idx] = 1.0f / fmaxf(sqrtf(nsq), 1e-12f);
}

// ---------------- build normalized masked-neighborhood Vt[n][j][k] (bf16 h/l) ----------------
__global__ __launch_bounds__(256) void vbuild_kernel(const ushort_t* __restrict__ ytpH,
                                                     const ushort_t* __restrict__ ytpL,
                                                     float* __restrict__ ws)
{
    size_t idx = (size_t)blockIdx.x * 256 + threadIdx.x; // (n*4096 + j)*512 + k
    int k = (int)(idx & 511);
    int j = (int)((idx >> 9) & 4095);
    int n = (int)(idx >> 21);
    int tp = k >> 7, c = k & 127;
    int h = j >> 6, w = j & 63;
    int dh, dw;
    if      (tp == 0) { dh = -1; dw = -1; }
    else if (tp == 1) { dh = -1; dw = 0;  }
    else if (tp == 2) { dh = -1; dw = 1;  }
    else              { dh = 0;  dw = -1; }
    size_t row = (size_t)n * 4624 + (size_t)(h + 2 + dh) * 68 + (w + 2 + dw);
    float v = (bf2f(ytpH[row * 128 + c]) + bf2f(ytpL[row * 128 + c]))
              * ws[WS_RNORM + ((size_t)n << 12) + j];
    ushort_t hi = f2bf_rne(v);
    ushort_t lo = f2bf_rne(v - bf2f(hi));
    ((ushort_t*)(ws + WS_VH))[idx] = hi;
    ((ushort_t*)(ws + WS_VL))[idx] = lo;
}

// ---------------- MFMA split-bf16 gram + per-tile column max/argmax ----------------
__global__ __launch_bounds__(256) void gram_mfma(const ushort_t* __restrict__ VH,
                                                 const ushort_t* __restrict__ VL,
                                                 float* __restrict__ pmax, int* __restrict__ parg)
{
    __shared__ __align__(16) ushort_t AsH[128 * 32];
    __shared__ __align__(16) ushort_t AsL[128 * 32];
    __shared__ __align__(16) ushort_t BsH[128 * 32];
    __shared__ __align__(16) ushort_t BsL[128 * 32];
    __shared__ float sredv[256];
    __shared__ int   sredi[256];

    int bx = blockIdx.x;
    int tb = (bx & 7) * 66 + (bx >> 3);   // bijective: 528 = 8*66
    int n = blockIdx.y;
    int jb = (int)((sqrtf(8.0f * (float)tb + 1.0f) - 1.0f) * 0.5f);
    while ((jb + 1) * (jb + 2) / 2 <= tb) ++jb;
    while (jb * (jb + 1) / 2 > tb) --jb;
    int ib = tb - jb * (jb + 1) / 2;

    int t = threadIdx.x, lane = t & 63, w = t >> 6;
    int wq_i = w >> 1, wq_j = w & 1;
    int fr = lane & 15, kg = lane >> 4;

    const ushort_t* vhn = VH + ((size_t)n << 21);
    const ushort_t* vln = VL + ((size_t)n << 21);

    int colq = lane >> 2, ks = lane & 3;
    int c0 = (w * 2 + 0) * 16 + colq;
    int c1 = (w * 2 + 1) * 16 + colq;
    size_t sA0 = ((size_t)(ib * 128 + c0)) * 512 + ks * 8;
    size_t sA1 = ((size_t)(ib * 128 + c1)) * 512 + ks * 8;
    size_t sB0 = ((size_t)(jb * 128 + c0)) * 512 + ks * 8;
    size_t sB1 = ((size_t)(jb * 128 + c1)) * 512 + ks * 8;
    int d0 = (w * 2 + 0) * 512;
    int d1 = (w * 2 + 1) * 512;

    f32x4 acc[4][4];
    #pragma unroll
    for (int mi = 0; mi < 4; ++mi)
        #pragma unroll
        for (int ni = 0; ni < 4; ++ni)
            acc[mi][ni] = (f32x4){0.f, 0.f, 0.f, 0.f};

    for (int k0 = 0; k0 < 512; k0 += 32) {
        gll16(vhn + sA0 + k0, &AsH[d0]);
        gll16(vhn + sA1 + k0, &AsH[d1]);
        gll16(vln + sA0 + k0, &AsL[d0]);
        gll16(vln + sA1 + k0, &AsL[d1]);
        gll16(vhn + sB0 + k0, &BsH[d0]);
        gll16(vhn + sB1 + k0, &BsH[d1]);
        gll16(vln + sB0 + k0, &BsL[d0]);
        gll16(vln + sB1 + k0, &BsL[d1]);
#ifdef HAVE_GLL
        asm volatile("s_waitcnt vmcnt(0)" ::: "memory");
#endif
        __syncthreads();

        bf16x8 ah[4], al[4], bh[4], bl[4];
        #pragma unroll
        for (int mi = 0; mi < 4; ++mi) {
            int col = wq_i * 64 + mi * 16 + fr;
            ah[mi] = *(const bf16x8*)&AsH[col * 32 + kg * 8];
            al[mi] = *(const bf16x8*)&AsL[col * 32 + kg * 8];
        }
        #pragma unroll
        for (int ni = 0; ni < 4; ++ni) {
            int col = wq_j * 64 + ni * 16 + fr;
            bh[ni] = *(const bf16x8*)&BsH[col * 32 + kg * 8];
            bl[ni] = *(const bf16x8*)&BsL[col * 32 + kg * 8];
        }
        #pragma unroll
        for (int mi = 0; mi < 4; ++mi)
            #pragma unroll
            for (int ni = 0; ni < 4; ++ni) {
                MFMA3(ah[mi], al[mi], bh[ni], bl[ni], acc[mi][ni]);
            }
        __syncthreads();
    }

    int i_base = ib * 128 + wq_i * 64;
    int j_base = jb * 128 + wq_j * 64;
    #pragma unroll
    for (int ni = 0; ni < 4; ++ni) {
        int j = j_base + ni * 16 + fr;
        float bv = -INFINITY; int bi = 0x7fffffff;
        #pragma unroll
        for (int mi = 0; mi < 4; ++mi)
            #pragma unroll
            for (int r = 0; r < 4; ++r) {
                int i = i_base + mi * 16 + kg * 4 + r;
                float v = acc[mi][ni][r];
                if (i < j && v > bv) { bv = v; bi = i; }
            }
        #pragma unroll
        for (int d = 16; d < 64; d <<= 1) {
            float ov = __shfl_xor(bv, d, 64);
            int   oi = __shfl_xor(bi, d, 64);
            if (ov > bv || (ov == bv && oi < bi)) { bv = ov; bi = oi; }
        }
        if (lane < 16) {
            sredv[wq_i * 128 + wq_j * 64 + ni * 16 + lane] = bv;
            sredi[wq_i * 128 + wq_j * 64 + ni * 16 + lane] = bi;
        }
    }
    __syncthreads();
    if (t < 128) {
        float v0 = sredv[t]; int i0 = sredi[t];
        float v1 = sredv[128 + t]; int i1 = sredi[128 + t];
        if (v1 > v0) { v0 = v1; i0 = i1; }
        pmax[(((size_t)n * 32 + ib) << 12) + jb * 128 + t] = v0;
        parg[(((size_t)n * 32 + ib) << 12) + jb * 128 + t] = i0;
    }
}

// ---------------- merged masked convs (conv5 | conv3) as implicit GEMM ----------------
// blockIdx.y<4: conv5 o-tile; else conv3 o-tile
__global__ __launch_bounds__(128) void conv_merged(
    const ushort_t* __restrict__ W5H, const ushort_t* __restrict__ W5L, const float* __restrict__ b5,
    const ushort_t* __restrict__ WrH, const ushort_t* __restrict__ WrL,
    const ushort_t* __restrict__ YH, const ushort_t* __restrict__ YL,
    ushort_t* __restrict__ locH, ushort_t* __restrict__ locL,
    ushort_t* __restrict__ ftH, ushort_t* __restrict__ ftL)
{
    __shared__ __align__(16) ushort_t AsH[64 * 32], AsL[64 * 32];
    __shared__ __align__(16) ushort_t BsH[128 * 32], BsL[128 * 32];
    int by = blockIdx.y;
    bool is5 = by < 4;
    const ushort_t* WH = is5 ? W5H : WrH;
    const ushort_t* WL = is5 ? W5L : WrL;
    const float* bias = is5 ? b5 : nullptr;
    uint64_t tapenc = is5 ? ENC5 : ENC3;
    int Ktot = is5 ? 1536 : 640;
    ushort_t* outH = is5 ? locH : ftH;
    ushort_t* outL = is5 ? locL : ftL;
    int o0 = (is5 ? by : by - 4) << 6;

    int t = threadIdx.x, w = t >> 6, lane = t & 63;
    int p0 = blockIdx.x << 7, n = blockIdx.z;
    int colq = lane >> 2, ks = lane & 3;
    int fr = lane & 15, kg = lane >> 4;
    int h0 = p0 >> 6;
    const ushort_t* yh = YH + (size_t)n * 4624 * 128;
    const ushort_t* yl = YL + (size_t)n * 4624 * 128;

    const ushort_t* aSrcH0 = WH + (size_t)(o0 + (2 * w + 0) * 16 + colq) * Ktot + ks * 8;
    const ushort_t* aSrcH1 = WH + (size_t)(o0 + (2 * w + 1) * 16 + colq) * Ktot + ks * 8;
    const ushort_t* aSrcL0 = WL + (size_t)(o0 + (2 * w + 0) * 16 + colq) * Ktot + ks * 8;
    const ushort_t* aSrcL1 = WL + (size_t)(o0 + (2 * w + 1) * 16 + colq) * Ktot + ks * 8;

    f32x4 acc[4][4];
    #pragma unroll
    for (int mi = 0; mi < 4; ++mi)
        #pragma unroll
        for (int ni = 0; ni < 4; ++ni) acc[mi][ni] = (f32x4){0.f, 0.f, 0.f, 0.f};

    for (int k0 = 0; k0 < Ktot; k0 += 32) {
        int tp = k0 >> 7, coff = (k0 & 127) + ks * 8;
        int f = (int)((tapenc >> (5 * tp)) & 31);
        int dh = (f & 3) - 2, dw = ((f >> 2) & 7) - 2;
        gll16(aSrcH0 + k0, &AsH[(2 * w + 0) * 512]);
        gll16(aSrcH1 + k0, &AsH[(2 * w + 1) * 512]);
        gll16(aSrcL0 + k0, &AsL[(2 * w + 0) * 512]);
        gll16(aSrcL1 + k0, &AsL[(2 * w + 1) * 512]);
        #pragma unroll
        for (int cb = 0; cb < 4; ++cb) {
            int c = w * 64 + cb * 16 + colq;
            int prow = (h0 + (c >> 6) + 2 + dh) * 68 + (c & 63) + 2 + dw;
            gll16(yh + (size_t)prow * 128 + coff, &BsH[(w * 4 + cb) * 512]);
            gll16(yl + (size_t)prow * 128 + coff, &BsL[(w * 4 + cb) * 512]);
        }
#ifdef HAVE_GLL
        asm volatile("s_waitcnt vmcnt(0)" ::: "memory");
#endif
        __syncthreads();
        bf16x8 ah[4], al[4], bh[4], bl[4];
        #pragma unroll
        for (int mi = 0; mi < 4; ++mi) {
            int col = mi * 16 + fr;
            ah[mi] = *(const bf16x8*)&AsH[col * 32 + kg * 8];
            al[mi] = *(const bf16x8*)&AsL[col * 32 + kg * 8];
        }
        #pragma unroll
        for (int ni = 0; ni < 4; ++ni) {
            int col = w * 64 + ni * 16 + fr;
            bh[ni] = *(const bf16x8*)&BsH[col * 32 + kg * 8];
            bl[ni] = *(const bf16x8*)&BsL[col * 32 + kg * 8];
        }
        #pragma unroll
        for (int mi = 0; mi < 4; ++mi)
            #pragma unroll
            for (int ni = 0; ni < 4; ++ni) {
                MFMA3(ah[mi], al[mi], bh[ni], bl[ni], acc[mi][ni]);
            }
        __syncthreads();
    }

    #pragma unroll
    for (int mi = 0; mi < 4; ++mi) {
        int og = o0 + mi * 16 + kg * 4;
        f32x4 bv = (f32x4){0.f, 0.f, 0.f, 0.f};
        if (bias) bv = *(const f32x4*)&bias[og];
        #pragma unroll
        for (int ni = 0; ni < 4; ++ni) {
            int p = p0 + w * 64 + ni * 16 + fr;
            f32x4 v = acc[mi][ni] + bv;
            ushort_t h0s = f2bf_rne(v[0]), h1s = f2bf_rne(v[1]), h2s = f2bf_rne(v[2]), h3s = f2bf_rne(v[3]);
            size_t db = (((size_t)n << 12) + p) * 256 + og;
            *(uint2*)&outH[db] = make_uint2(h0s | ((uint32_t)h1s << 16), h2s | ((uint32_t)h3s << 16));
            ushort_t l0s = f2bf_rne(v[0] - bf2f(h0s)), l1s = f2bf_rne(v[1] - bf2f(h1s));
            ushort_t l2s = f2bf_rne(v[2] - bf2f(h2s)), l3s = f2bf_rne(v[3] - bf2f(h3s));
            *(uint2*)&outL[db] = make_uint2(l0s | ((uint32_t)l1s << 16), l2s | ((uint32_t)l3s << 16));
        }
    }
}

// ---------------- merged rf projections (P2T | P3T), f32 [n][4096][128] out ----------------
__global__ __launch_bounds__(128) void dense_merged(
    const ushort_t* __restrict__ W2H, const ushort_t* __restrict__ W2L,
    const ushort_t* __restrict__ W3H, const ushort_t* __restrict__ W3L,
    const ushort_t* __restrict__ B0H, const ushort_t* __restrict__ B0L,
    float* __restrict__ p2t, float* __restrict__ p3t)
{
    __shared__ __align__(16) ushort_t AsH[64 * 32], AsL[64 * 32];
    __shared__ __align__(16) ushort_t BsH[128 * 32], BsL[128 * 32];
    int by = blockIdx.y;
    const ushort_t* WH = (by < 2) ? W2H : W3H;
    const ushort_t* WL = (by < 2) ? W2L : W3L;
    float* outF = (by < 2) ? p2t : p3t;
    int o0 = (by & 1) << 6;
    constexpr int Ktot = 256;

    int t = threadIdx.x, w = t >> 6, lane = t & 63;
    int p0 = blockIdx.x << 7, n = blockIdx.z;
    int colq = lane >> 2, ks = lane & 3;
    int fr = lane & 15, kg = lane >> 4;

    const ushort_t* aSrcH0 = WH + (size_t)(o0 + (2 * w + 0) * 16 + colq) * Ktot + ks * 8;
    const ushort_t* aSrcH1 = WH + (size_t)(o0 + (2 * w + 1) * 16 + colq) * Ktot + ks * 8;
    const ushort_t* aSrcL0 = WL + (size_t)(o0 + (2 * w + 0) * 16 + colq) * Ktot + ks * 8;
    const ushort_t* aSrcL1 = WL + (size_t)(o0 + (2 * w + 1) * 16 + colq) * Ktot + ks * 8;
    size_t brow[4];
    #pragma unroll
    for (int cb = 0; cb < 4; ++cb)
        brow[cb] = ((size_t)n << 12) + p0 + w * 64 + cb * 16 + colq;

    f32x4 acc[4][4];
    #pragma unroll
    for (int mi = 0; mi < 4; ++mi)
        #pragma unroll
        for (int ni = 0; ni < 4; ++ni) acc[mi][ni] = (f32x4){0.f, 0.f, 0.f, 0.f};

    for (int k0 = 0; k0 < Ktot; k0 += 32) {
        gll16(aSrcH0 + k0, &AsH[(2 * w + 0) * 512]);
        gll16(aSrcH1 + k0, &AsH[(2 * w + 1) * 512]);
        gll16(aSrcL0 + k0, &AsL[(2 * w + 0) * 512]);
        gll16(aSrcL1 + k0, &AsL[(2 * w + 1) * 512]);
        int kk = k0 + ks * 8;
        #pragma unroll
        for (int cb = 0; cb < 4; ++cb) {
            gll16(B0H + brow[cb] * 256 + kk, &BsH[(w * 4 + cb) * 512]);
            gll16(B0L + brow[cb] * 256 + kk, &BsL[(w * 4 + cb) * 512]);
        }
#ifdef HAVE_GLL
        asm volatile("s_waitcnt vmcnt(0)" ::: "memory");
#endif
        __syncthreads();
        bf16x8 ah[4], al[4], bh[4], bl[4];
        #pragma unroll
        for (int mi = 0; mi < 4; ++mi) {
            int col = mi * 16 + fr;
            ah[mi] = *(const bf16x8*)&AsH[col * 32 + kg * 8];
            al[mi] = *(const bf16x8*)&AsL[col * 32 + kg * 8];
        }
        #pragma unroll
        for (int ni = 0; ni < 4; ++ni) {
            int col = w * 64 + ni * 16 + fr;
            bh[ni] = *(const bf16x8*)&BsH[col * 32 + kg * 8];
            bl[ni] = *(const bf16x8*)&BsL[col * 32 + kg * 8];
        }
        #pragma unroll
        for (int mi = 0; mi < 4; ++mi)
            #pragma unroll
            for (int ni = 0; ni < 4; ++ni) {
                MFMA3(ah[mi], al[mi], bh[ni], bl[ni], acc[mi][ni]);
            }
        __syncthreads();
    }

    #pragma unroll
    for (int mi = 0; mi < 4; ++mi) {
        int og = o0 + mi * 16 + kg * 4;
        #pragma unroll
        for (int ni = 0; ni < 4; ++ni) {
            int p = p0 + w * 64 + ni * 16 + fr;
            *(f32x4*)&outF[(((size_t)n << 12) + p) * 128 + og] = acc[mi][ni];
        }
    }
}

// ---------------- fused 3-layer MLP (P-tile 64, 4 waves) ----------------
struct MlpCfg {
    const ushort_t *waH, *waL; const float* ba; int Ka;
    const ushort_t *wbH, *wbL; const float* bb;
    const ushort_t *wcH, *wcL; const float* bc;
    const ushort_t *x0H, *x0L; int k0len, str0;
    const ushort_t *x1H, *x1L; int str1;
    const float* gatherP; int addLsu;
    float* outBase;
};

__global__ __launch_bounds__(256) void mlp_fused(MlpCfg c0, MlpCfg c1,
    const int* __restrict__ argi, const float* __restrict__ lsu)
{
    __shared__ __align__(16) ushort_t hbH[8192];
    __shared__ __align__(16) ushort_t hbL[8192];
    const MlpCfg c = blockIdx.y ? c1 : c0;
    int t = threadIdx.x, lane = t & 63, w = t >> 6;
    int fr = lane & 15, kg = lane >> 4;
    int p0 = blockIdx.x << 6, n = blockIdx.z;
    int o_t = w >> 1, p_h = w & 1;

    // ---- L1: O=128, K=Ka, leaky, optional gather -> hbuf
    {
        f32x4 acc[4][2];
        #pragma unroll
        for (int mi = 0; mi < 4; ++mi)
            #pragma unroll
            for (int ni = 0; ni < 2; ++ni) acc[mi][ni] = (f32x4){0.f, 0.f, 0.f, 0.f};
        for (int k0 = 0; k0 < c.Ka; k0 += 32) {
            const ushort_t *xh, *xl; int kk, str;
            if (k0 < c.k0len) { xh = c.x0H; xl = c.x0L; kk = k0; str = c.str0; }
            else              { xh = c.x1H; xl = c.x1L; kk = k0 - c.k0len; str = c.str1; }
            kk += kg * 8;
            bf16x8 ah[4], al[4], bh[2], bl[2];
            #pragma unroll
            for (int ni = 0; ni < 2; ++ni) {
                size_t row = ((size_t)n << 12) + p0 + p_h * 32 + ni * 16 + fr;
                bh[ni] = *(const bf16x8*)&xh[row * str + kk];
                bl[ni] = *(const bf16x8*)&xl[row * str + kk];
            }
            #pragma unroll
            for (int mi = 0; mi < 4; ++mi) {
                size_t orow = (size_t)(o_t * 64 + mi * 16 + fr) * c.Ka + k0 + kg * 8;
                ah[mi] = *(const bf16x8*)&c.waH[orow];
                al[mi] = *(const bf16x8*)&c.waL[orow];
            }
            #pragma unroll
            for (int mi = 0; mi < 4; ++mi)
                #pragma unroll
                for (int ni = 0; ni < 2; ++ni) {
                    MFMA3(ah[mi], al[mi], bh[ni], bl[ni], acc[mi][ni]);
                }
        }
        #pragma unroll
        for (int mi = 0; mi < 4; ++mi) {
            int og = o_t * 64 + mi * 16 + kg * 4;
            f32x4 bv = *(const f32x4*)&c.ba[og];
            #pragma unroll
            for (int ni = 0; ni < 2; ++ni) {
                int p_loc = p_h * 32 + ni * 16 + fr;
                int p = p0 + p_loc;
                f32x4 v = acc[mi][ni] + bv;
                if (c.gatherP) {
                    int aj = argi[(n << 12) + p];
                    if (aj >= 0) v += *(const f32x4*)&c.gatherP[(((size_t)n << 12) + aj) * 128 + og];
                }
                #pragma unroll
                for (int r = 0; r < 4; ++r) v[r] = v[r] > 0.f ? v[r] : 0.2f * v[r];
                int osw = og ^ ((p_loc & 7) << 3);
                ushort_t h0s = f2bf_rne(v[0]), h1s = f2bf_rne(v[1]), h2s = f2bf_rne(v[2]), h3s = f2bf_rne(v[3]);
                *(uint2*)&hbH[p_loc * 128 + osw] = make_uint2(h0s | ((uint32_t)h1s << 16), h2s | ((uint32_t)h3s << 16));
                ushort_t l0s = f2bf_rne(v[0] - bf2f(h0s)), l1s = f2bf_rne(v[1] - bf2f(h1s));
                ushort_t l2s = f2bf_rne(v[2] - bf2f(h2s)), l3s = f2bf_rne(v[3] - bf2f(h3s));
                *(uint2*)&hbL[p_loc * 128 + osw] = make_uint2(l0s | ((uint32_t)l1s << 16), l2s | ((uint32_t)l3s << 16));
            }
        }
    }
    __syncthreads();
    // ---- L2: 128x128 from hbuf, leaky -> hbuf
    {
        f32x4 acc[4][2];
        #pragma unroll
        for (int mi = 0; mi < 4; ++mi)
            #pragma unroll
            for (int ni = 0; ni < 2; ++ni) acc[mi][ni] = (f32x4){0.f, 0.f, 0.f, 0.f};
        for (int k0 = 0; k0 < 128; k0 += 32) {
            bf16x8 ah[4], al[4], bh[2], bl[2];
            #pragma unroll
            for (int ni = 0; ni < 2; ++ni) {
                int p_loc = p_h * 32 + ni * 16 + fr;
                int koff = (k0 + kg * 8) ^ ((p_loc & 7) << 3);
                bh[ni] = *(const bf16x8*)&hbH[p_loc * 128 + koff];
                bl[ni] = *(const bf16x8*)&hbL[p_loc * 128 + koff];
            }
            #pragma unroll
            for (int mi = 0; mi < 4; ++mi) {
                size_t orow = (size_t)(o_t * 64 + mi * 16 + fr) * 128 + k0 + kg * 8;
                ah[mi] = *(const bf16x8*)&c.wbH[orow];
                al[mi] = *(const bf16x8*)&c.wbL[orow];
            }
            #pragma unroll
            for (int mi = 0; mi < 4; ++mi)
                #pragma unroll
                for (int ni = 0; ni < 2; ++ni) {
                    MFMA3(ah[mi], al[mi], bh[ni], bl[ni], acc[mi][ni]);
                }
        }
        __syncthreads();
        #pragma unroll
        for (int mi = 0; mi < 4; ++mi) {
            int og = o_t * 64 + mi * 16 + kg * 4;
            f32x4 bv = *(const f32x4*)&c.bb[og];
            #pragma unroll
            for (int ni = 0; ni < 2; ++ni) {
                int p_loc = p_h * 32 + ni * 16 + fr;
                f32x4 v = acc[mi][ni] + bv;
                #pragma unroll
                for (int r = 0; r < 4; ++r) v[r] = v[r] > 0.f ? v[r] : 0.2f * v[r];
                int osw = og ^ ((p_loc & 7) << 3);
                ushort_t h0s = f2bf_rne(v[0]), h1s = f2bf_rne(v[1]), h2s = f2bf_rne(v[2]), h3s = f2bf_rne(v[3]);
                *(uint2*)&hbH[p_loc * 128 + osw] = make_uint2(h0s | ((uint32_t)h1s << 16), h2s | ((uint32_t)h3s << 16));
                ushort_t l0s = f2bf_rne(v[0] - bf2f(h0s)), l1s = f2bf_rne(v[1] - bf2f(h1s));
                ushort_t l2s = f2bf_rne(v[2] - bf2f(h2s)), l3s = f2bf_rne(v[3] - bf2f(h3s));
                *(uint2*)&hbL[p_loc * 128 + osw] = make_uint2(l0s | ((uint32_t)l1s << 16), l2s | ((uint32_t)l3s << 16));
            }
        }
    }
    __syncthreads();
    // ---- L3: O=384 -> 12 units of 64x32, 3 per wave; -> global f32
    for (int it = 0; it < 3; ++it) {
        int u = w + 4 * it;
        int o3 = u >> 1, p3 = u & 1;
        f32x4 acc[4][2];
        #pragma unroll
        for (int mi = 0; mi < 4; ++mi)
            #pragma unroll
            for (int ni = 0; ni < 2; ++ni) acc[mi][ni] = (f32x4){0.f, 0.f, 0.f, 0.f};
        for (int k0 = 0; k0 < 128; k0 += 32) {
            bf16x8 ah[4], al[4], bh[2], bl[2];
            #pragma unroll
            for (int ni = 0; ni < 2; ++ni) {
                int p_loc = p3 * 32 + ni * 16 + fr;
                int koff = (k0 + kg * 8) ^ ((p_loc & 7) << 3);
                bh[ni] = *(const bf16x8*)&hbH[p_loc * 128 + koff];
                bl[ni] = *(const bf16x8*)&hbL[p_loc * 128 + koff];
            }
            #pragma unroll
            for (int mi = 0; mi < 4; ++mi) {
                size_t orow = (size_t)(o3 * 64 + mi * 16 + fr) * 128 + k0 + kg * 8;
                ah[mi] = *(const bf16x8*)&c.wcH[orow];
                al[mi] = *(const bf16x8*)&c.wcL[orow];
            }
            #pragma unroll
            for (int mi = 0; mi < 4; ++mi)
                #pragma unroll
                for (int ni = 0; ni < 2; ++ni) {
                    MFMA3(ah[mi], al[mi], bh[ni], bl[ni], acc[mi][ni]);
                }
        }
        #pragma unroll
        for (int mi = 0; mi < 4; ++mi) {
            int og = o3 * 64 + mi * 16 + kg * 4;
            f32x4 bv = *(const f32x4*)&c.bc[og];
            #pragma unroll
            for (int ni = 0; ni < 2; ++ni) {
                int p = p0 + p3 * 32 + ni * 16 + fr;
                f32x4 v = acc[mi][ni] + bv;
                if (c.addLsu && og < 128) {
                    float lv = lsu[(n << 12) + p];
                    v[0] += lv; v[1] += lv; v[2] += lv; v[3] += lv;
                }
                float* dst = c.outBase + (((size_t)(n * 384 + og)) << 12) + p;
                dst[0] = v[0]; dst[4096] = v[1]; dst[8192] = v[2]; dst[12288] = v[3];
            }
        }
    }
}

// ---------------- y_prob from para1 (coalesced, 4 ch-groups) ----------------
__global__ __launch_bounds__(256) void yprob_kernel(
    const float* __restrict__ out, const float* __restrict__ y, float* __restrict__ ws)
{
    __shared__ float red[4][64];
    int n = blockIdx.y, t = threadIdx.x;
    int pl = t & 63, cg = t >> 6;
    int p = (blockIdx.x << 6) + pl;
    const float* bw = out + OUT_P1 + ((size_t)(n * 384 + cg * 32) << 12) + p;
    const float* bm = bw + ((size_t)128 << 12);
    const float* bs = bm + ((size_t)128 << 12);
    const float* by_ = y + ((size_t)(n * 128 + cg * 32) << 12) + p;
    float acc = 0.f;
    for (int cc = 0; cc < 32; ++cc) {
        float w  = bw[(size_t)cc << 12];
        float mu = bm[(size_t)cc << 12];
        float ls = bs[(size_t)cc << 12];
        float yv = by_[(size_t)cc << 12];
        ls = fminf(fmaxf(ls, -7.f), 7.f);
        float tt = (yv - mu) * expf(-ls);
        float lsig = (w >= 0.f) ? -log1pf(expf(-w)) : (w - log1pf(expf(w)));
        float nll = 0.5f * tt * tt + ls + 0.9189385f - lsig;
        acc += expf(-nll);
    }
    red[cg][pl] = acc;
    __syncthreads();
    if (t < 64)
        ws[WS_YPROB + ((size_t)n << 12) + (blockIdx.x << 6) + t] =
            (red[0][t] + red[1][t] + red[2][t] + red[3][t]) * (1.0f / 128.0f);
}

// ---------------- merge tile partials, emit S/U/R_arg ----------------
__global__ __launch_bounds__(256) void finalize_kernel(float* __restrict__ ws, float* __restrict__ out)
{
    int idx = blockIdx.x * 256 + threadIdx.x;
    int n = idx >> 12, j = idx & 4095;
    float s, u; int a;
    if (j == 0) { s = 1e-8f; u = 1e-8f; a = -1; }
    else {
        float bv = -INFINITY; int bi = 0x7fffffff;
        const int* pai = (const int*)ws;
        int jbt = j >> 7;
        for (int ib = 0; ib <= jbt; ++ib) {
            float v = ws[WS_PMAX + (((size_t)n * 32 + ib) << 12) + j];
            int ii = pai[WS_PARG + (((size_t)n * 32 + ib) << 12) + j];
            if (v > bv || (v == bv && ii < bi)) { bv = v; bi = ii; }
        }
        s = fminf(fmaxf(bv, 1e-8f), 1.0f);
        if (bi < 0 || bi > 4095) bi = 0;
        float yp = ws[WS_YPROB + ((size_t)n << 12) + bi];
        u = fminf(fmaxf(yp, 1e-8f), 1.0f);
        a = bi;
    }
    out[OUT_S + idx] = s;
    out[OUT_U + idx] = u;
    out[OUT_RA + idx] = (float)a;
    ((int*)ws)[WS_ARGI + idx] = a;
    ws[WS_LSU + idx] = logf(s + 1e-8f) + logf(u + 1e-8f);
}

// ---------------- launch ----------------
extern "C" void kernel_launch(void* const* d_in, const int* in_sizes, int n_in,
                              void* d_out, int out_size, void* d_ws, size_t ws_size,
                              hipStream_t stream)
{
    const float* y   = (const float*)d_in[0];
    const float* z   = (const float*)d_in[1];
    const float* w5  = (const float*)d_in[2];
    const float* b5  = (const float*)d_in[3];
    const float* w1a = (const float*)d_in[4];
    const float* b1a = (const float*)d_in[5];
    const float* w1b = (const float*)d_in[6];
    const float* b1b = (const float*)d_in[7];
    const float* w1c = (const float*)d_in[8];
    const float* b1c = (const float*)d_in[9];
    const float* wrf = (const float*)d_in[10];
    const float* w2a = (const float*)d_in[11];
    const float* b2a = (const float*)d_in[12];
    const float* w2b = (const float*)d_in[13];
    const float* b2b = (const float*)d_in[14];
    const float* w2c = (const float*)d_in[15];
    const float* b2c = (const float*)d_in[16];
    const float* w3a = (const float*)d_in[17];
    const float* b3a = (const float*)d_in[18];
    const float* w3b = (const float*)d_in[19];
    const float* b3b = (const float*)d_in[20];
    const float* w3c = (const float*)d_in[21];
    const float* b3c = (const float*)d_in[22];
    float* ws  = (float*)d_ws;
    float* out = (float*)d_out;
    const int* argi = (const int*)(ws) + WS_ARGI;

    ushort_t* wph = (ushort_t*)(ws + WS_WPK);
    ushort_t* wpl = wph + 933888;
    ushort_t* locH = (ushort_t*)(ws + WS_LOCH);
    ushort_t* locL = (ushort_t*)(ws + WS_LOCL);
    ushort_t* ftH  = (ushort_t*)(ws + WS_FTH);
    ushort_t* ftL  = (ushort_t*)(ws + WS_FTL);
    float* p2t = ws + WS_P2T;
    float* p3t = ws + WS_P3T;
    ushort_t* ztpH = (ushort_t*)(ws + WS_ZTPH);
    ushort_t* ztpL = (ushort_t*)(ws + WS_ZTPL);
    ushort_t* ytpH = (ushort_t*)(out + OS_YTPH);
    ushort_t* ytpL = (ushort_t*)(out + OS_YTPL);

    prep_fused<<<5960, 256, 0, stream>>>(w5, wrf, w1a, w1b, w1c, w2a, w2b, w2c, w3a, w3b, w3c,
                                         y, z, wph, wpl, ytpH, ytpL, ztpH, ztpL);
    sumsq_kernel<<<dim3(64, NB), 256, 0, stream>>>(y, ws);
    rnorm_kernel<<<64, 256, 0, stream>>>(ws);
    vbuild_kernel<<<32768, 256, 0, stream>>>(ytpH, ytpL, ws);
    gram_mfma<<<dim3(528, NB), 256, 0, stream>>>((const ushort_t*)(ws + WS_VH), (const ushort_t*)(ws + WS_VL),
                                                 ws + WS_PMAX, (int*)(ws + WS_PARG));

    // conv5 -> localT, conv3 -> FT (overwrites V; gram done, stream-ordered)
    conv_merged<<<dim3(32, 8, NB), 128, 0, stream>>>(wph + WP_W5, wpl + WP_W5, b5,
                                                     wph + WP_WR, wpl + WP_WR,
                                                     ytpH, ytpL, locH, locL, ftH, ftL);
    // rf projections -> P2T/P3T
    dense_merged<<<dim3(32, 4, NB), 128, 0, stream>>>(wph + WP_W2AR, wpl + WP_W2AR,
                                                      wph + WP_W3AR, wpl + WP_W3AR,
                                                      ftH, ftL, p2t, p3t);

    // mlp1 fused -> para1
    MlpCfg m1;
    m1.waH = wph + WP_W1A; m1.waL = wpl + WP_W1A; m1.ba = b1a; m1.Ka = 256;
    m1.wbH = wph + WP_W1B; m1.wbL = wpl + WP_W1B; m1.bb = b1b;
    m1.wcH = wph + WP_W1C; m1.wcL = wpl + WP_W1C; m1.bc = b1c;
    m1.x0H = locH; m1.x0L = locL; m1.k0len = 256; m1.str0 = 256;
    m1.x1H = locH; m1.x1L = locL; m1.str1 = 256;
    m1.gatherP = nullptr; m1.addLsu = 0; m1.outBase = out + OUT_P1;
    mlp_fused<<<dim3(64, 1, NB), 256, 0, stream>>>(m1, m1, argi, ws + WS_LSU);

    yprob_kernel<<<dim3(64, NB), 256, 0, stream>>>(out, y, ws);
    finalize_kernel<<<64, 256, 0, stream>>>(ws, out);

    // mlp2 + mlp3 fused (single launch, blockIdx.y selects)
    MlpCfg m2;
    m2.waH = wph + WP_W2AL; m2.waL = wpl + WP_W2AL; m2.ba = b2a; m2.Ka = 256;
    m2.wbH = wph + WP_W2B; m2.wbL = wpl + WP_W2B; m2.bb = b2b;
    m2.wcH = wph + WP_W2C; m2.wcL = wpl + WP_W2C; m2.bc = b2c;
    m2.x0H = locH; m2.x0L = locL; m2.k0len = 256; m2.str0 = 256;
    m2.x1H = locH; m2.x1L = locL; m2.str1 = 256;
    m2.gatherP = p2t; m2.addLsu = 1; m2.outBase = out + OUT_P2;
    MlpCfg m3;
    m3.waH = wph + WP_W3ALZ; m3.waL = wpl + WP_W3ALZ; m3.ba = b3a; m3.Ka = 384;
    m3.wbH = wph + WP_W3B; m3.wbL = wpl + WP_W3B; m3.bb = b3b;
    m3.wcH = wph + WP_W3C; m3.wcL = wpl + WP_W3C; m3.bc = b3c;
    m3.x0H = locH; m3.x0L = locL; m3.k0len = 256; m3.str0 = 256;
    m3.x1H = ztpH; m3.x1L = ztpL; m3.str1 = 128;
    m3.gatherP = p3t; m3.addLsu = 0; m3.outBase = out + OUT_P3;
    mlp_fused<<<dim3(64, 2, NB), 256, 0, stream>>>(m2, m3, argi, ws + WS_LSU);

    (void)in_sizes; (void)n_in; (void)out_size; (void)ws_size;
}